// Round 18
// baseline (37.117 us; speedup 1.0000x reference)
//
#include <hip/hip_runtime.h>
#include <math.h>

#define F_IN  128
#define F_OUT 256
#define GBITS 5            // 32 nodes per group
#define G_MAX 380          // max groups (G = ceil(n/32) = 375 for n=12000)
#define WPR   376          // padded words per LDS bitmap row (>= ceil(n/32))
#define SBLK  128          // scatter blocks (dedup assumes 2 threads/run -> 256)
#define STHR  512          // scatter threads per block
#define STAGE_CAP 8192     // LDS staging items per scatter block (32 KB)
#define SACC_STRIDE 8      // int64 slots per s[k] (one 64B line each)
#define SCALE 4294967296.0 // 2^32 fixed-point scale

// ---------------------------------------------------------------------------
// S: block-region scatter (R17-verified). Block 0 additionally zeroes the
// global integer accumulator sacc (visible to dedup via the kernel boundary).
// ---------------------------------------------------------------------------
__global__ __launch_bounds__(STHR)
void k_scatter_blockout(const int* __restrict__ ei, int E, int G,
                        int* __restrict__ lofs_t,        // [(G+1)][SBLK]
                        unsigned* __restrict__ blockout, // [SBLK][rcap]
                        unsigned long long* __restrict__ sacc, // [F_IN*SACC_STRIDE]
                        int rcap) {
    __shared__ int hist[G_MAX];
    __shared__ int cur[G_MAX];
    __shared__ int sc[STHR];
    __shared__ unsigned stage[STAGE_CAP];          // 32 KB
    int b = blockIdx.x, t = threadIdx.x;

    if (b == 0 && t < F_IN) sacc[t * SACC_STRIDE] = 0ull;

    for (int g = t; g < G; g += STHR) hist[g] = 0;
    __syncthreads();

    int C = (E + (int)gridDim.x - 1) / (int)gridDim.x;
    int e0 = b * C, e1 = min(E, e0 + C);
    for (int e = e0 + t; e < e1; e += STHR) {
        int a = ei[e], c = ei[E + e];
        atomicAdd(&hist[a >> GBITS], 1);
        atomicAdd(&hist[c >> GBITS], 1);
    }
    __syncthreads();

    sc[t] = (t < G) ? hist[t] : 0;
    __syncthreads();
    #pragma unroll
    for (int d = 1; d < STHR; d <<= 1) {
        int v = (t >= d) ? sc[t - d] : 0;
        __syncthreads();
        sc[t] += v;
        __syncthreads();
    }
    if (t < G) {
        int lo = sc[t] - hist[t];                  // exclusive prefix
        cur[t] = lo;
        lofs_t[(size_t)t * SBLK + b] = lo;
    }
    if (t == 0) lofs_t[(size_t)G * SBLK + b] = sc[STHR - 1];
    __syncthreads();

    for (int e = e0 + t; e < e1; e += STHR) {
        int a = ei[e], c = ei[E + e];
        int s1 = atomicAdd(&cur[a >> GBITS], 1);
        stage[s1] = ((unsigned)a << 16) | (unsigned)c;
        int s2 = atomicAdd(&cur[c >> GBITS], 1);
        stage[s2] = ((unsigned)c << 16) | (unsigned)a;
    }
    __syncthreads();

    int tot = sc[STHR - 1];
    unsigned* myout = blockout + (size_t)b * rcap;
    for (int s = t; s < tot; s += STHR)
        myout[s] = stage[s];
}

// ---------------------------------------------------------------------------
// D: per group of 32 nodes (insert/count phases byte-identical to R17).
// The block's colsum partial (fixed-order float tree -> deterministic) is
// committed via int64 fixed-point atomicAdd (integer = order-invariant =>
// bitwise-deterministic global sum; no fences; error <= 2^-33 per block).
// ---------------------------------------------------------------------------
union DedupLds {
    unsigned bm[32 * WPR];        // 48128 B (insert phase)
    float4   red[8][32];          // 4 KB   (colsum reduce; bm dead)
};

__global__ __launch_bounds__(256)
void k_dedup_colsum(const unsigned* __restrict__ blockout,
                    const int* __restrict__ lofs_t, int rcap,
                    const float4* __restrict__ x4,
                    float* __restrict__ dinv,
                    unsigned long long* __restrict__ sacc,
                    int n, int G) {
    __shared__ DedupLds u;
    __shared__ int dcnt[32];
    __shared__ float dloc[32];
    int g = blockIdx.x, t = threadIdx.x;

    uint4* bm4 = (uint4*)u.bm;
    for (int i = t; i < (32 * WPR) / 4; i += 256)
        bm4[i] = make_uint4(0u, 0u, 0u, 0u);
    if (t < 32) dcnt[t] = 0;
    __syncthreads();

    {
        int b = t >> 1, half = t & 1;
        int lo = lofs_t[(size_t)g       * SBLK + b];
        int hi = lofs_t[(size_t)(g + 1) * SBLK + b];
        const unsigned* mo = blockout + (size_t)b * rcap;
        for (int i = lo + half; i < hi; i += 2) {
            unsigned w = mo[i];
            unsigned lrow = (w >> 16) & 31u, col = w & 0xFFFFu;
            unsigned bit = 1u << (col & 31);
            unsigned old = atomicOr(&u.bm[lrow * WPR + (col >> 5)], bit);
            if (!(old & bit)) atomicAdd(&dcnt[lrow], 1);
        }
    }
    __syncthreads();

    if (t < 32) {
        float dv = 1.0f / sqrtf((float)dcnt[t]);   // deg==0 -> inf, matches ref
        dloc[t] = dv;
        int node = g * 32 + t;
        if (node < n) dinv[node] = dv;
    }
    __syncthreads();

    int c4 = t & 31, ro = t >> 5;         // ro 0..7
    float4 acc = make_float4(0.f, 0.f, 0.f, 0.f);
    for (int lr = ro; lr < 32; lr += 8) {
        int node = g * 32 + lr;
        if (node >= n) break;
        float dv = dloc[lr];
        float4 v = x4[(size_t)node * (F_IN / 4) + c4];
        acc.x += dv * v.x; acc.y += dv * v.y;
        acc.z += dv * v.z; acc.w += dv * v.w;
    }
    __syncthreads();                      // bm reads done; reuse LDS as scratch
    u.red[ro][c4] = acc;
    __syncthreads();
    if (ro == 0) {
        float4 s = u.red[0][c4];
        #pragma unroll
        for (int k = 1; k < 8; ++k) {
            float4 v = u.red[k][c4];
            s.x += v.x; s.y += v.y; s.z += v.z; s.w += v.w;
        }
        // int64 fixed-point commit: one 64B line per s[k]
        atomicAdd(&sacc[(c4 * 4 + 0) * SACC_STRIDE],
                  (unsigned long long)(long long)llrint((double)s.x * SCALE));
        atomicAdd(&sacc[(c4 * 4 + 1) * SACC_STRIDE],
                  (unsigned long long)(long long)llrint((double)s.y * SCALE));
        atomicAdd(&sacc[(c4 * 4 + 2) * SACC_STRIDE],
                  (unsigned long long)(long long)llrint((double)s.z * SCALE));
        atomicAdd(&sacc[(c4 * 4 + 3) * SACC_STRIDE],
                  (unsigned long long)(long long)llrint((double)s.w * SCALE));
    }
}

// ---------------------------------------------------------------------------
// O (fused): per block — decode s from sacc, GEMV agg = s·W (coalesced W
// reads, thread t owns column t, shared via LDS), then grid-stride output:
// out[n,f] = dinv[n]*agg[f] + bias[f].
// ---------------------------------------------------------------------------
__global__ __launch_bounds__(256)
void k_gemv_outer(const unsigned long long* __restrict__ sacc,
                  const float* __restrict__ W, const float* __restrict__ bias,
                  const float* __restrict__ dinv,
                  float4* __restrict__ out4, int n) {
    __shared__ float s[F_IN];
    __shared__ __align__(16) float aggL[F_OUT];
    int t = threadIdx.x;
    if (t < F_IN)
        s[t] = (float)((double)(long long)sacc[t * SACC_STRIDE] * (1.0 / SCALE));
    __syncthreads();

    {   // thread t -> output column t (coalesced W row reads)
        float a = 0.f;
        #pragma unroll 8
        for (int k = 0; k < F_IN; ++k)
            a = fmaf(s[k], W[(size_t)k * F_OUT + t], a);
        aggL[t] = a;
    }
    __syncthreads();

    int f4 = t & 63;                      // invariant: grid stride % 64 == 0
    float4 ag = ((const float4*)aggL)[f4];
    float4 b4 = ((const float4*)bias)[f4];
    int total4 = n * (F_OUT / 4);
    int gs = (int)gridDim.x * 256;
    for (int i = (int)blockIdx.x * 256 + t; i < total4; i += gs) {
        float d = dinv[i >> 6];           // 64 consecutive lanes share node
        float4 o;
        o.x = fmaf(d, ag.x, b4.x);
        o.y = fmaf(d, ag.y, b4.y);
        o.z = fmaf(d, ag.z, b4.z);
        o.w = fmaf(d, ag.w, b4.w);
        out4[i] = o;
    }
}

// ===========================================================================
// Fallback (odd sizes / tiny workspace): round-4 global-bitmap path.
// ===========================================================================
__global__ __launch_bounds__(256)
void k_zero_simple(float4* __restrict__ p, size_t n4) {
    size_t i = (size_t)blockIdx.x * blockDim.x + threadIdx.x;
    size_t stride = (size_t)gridDim.x * blockDim.x;
    float4 z = make_float4(0.f, 0.f, 0.f, 0.f);
    for (; i < n4; i += stride) p[i] = z;
}
__global__ void k_set_bits_simple(const int* __restrict__ ei, int E,
                                  unsigned* __restrict__ bm, int r0, int r1,
                                  int row_words) {
    int e = blockIdx.x * blockDim.x + threadIdx.x;
    if (e >= E) return;
    int a = ei[e];
    int b = ei[E + e];
    if (a >= r0 && a < r1)
        atomicOr(&bm[(size_t)(a - r0) * row_words + (b >> 5)], 1u << (b & 31));
    if (b >= r0 && b < r1)
        atomicOr(&bm[(size_t)(b - r0) * row_words + (a >> 5)], 1u << (a & 31));
}
__global__ __launch_bounds__(256)
void k_degree_simple(const unsigned* __restrict__ bm, float* __restrict__ dinv,
                     int r0, int rows, int row_words) {
    int wave = threadIdx.x >> 6;
    int lane = threadIdx.x & 63;
    int row  = blockIdx.x * 4 + wave;
    if (row >= rows) return;
    const unsigned* p = bm + (size_t)row * row_words;
    int cnt = 0;
    for (int w = lane; w < row_words; w += 64)
        cnt += __popc(p[w]);
    #pragma unroll
    for (int off = 32; off > 0; off >>= 1)
        cnt += __shfl_down(cnt, off, 64);
    if (lane == 0)
        dinv[r0 + row] = 1.0f / sqrtf((float)cnt);
}
__global__ __launch_bounds__(256)
void k_colsum_simple(const float4* __restrict__ x4, const float* __restrict__ dinv,
                     float4* __restrict__ partial4, int n) {
    __shared__ float4 lds[8][32];
    int t = threadIdx.x;
    int c4 = t & 31;
    int ro = t >> 5;
    int rows_per = (n + (int)gridDim.x - 1) / (int)gridDim.x;
    int rbeg = blockIdx.x * rows_per;
    int rend = rbeg + rows_per; if (rend > n) rend = n;
    float4 acc = make_float4(0.f, 0.f, 0.f, 0.f);
    for (int r = rbeg + ro; r < rend; r += 8) {
        float dv = dinv[r];
        float4 v = x4[(size_t)r * (F_IN / 4) + c4];
        acc.x += dv * v.x; acc.y += dv * v.y;
        acc.z += dv * v.z; acc.w += dv * v.w;
    }
    lds[ro][c4] = acc;
    __syncthreads();
    if (ro == 0) {
        float4 s = lds[0][c4];
        #pragma unroll
        for (int g = 1; g < 8; ++g) {
            float4 v = lds[g][c4];
            s.x += v.x; s.y += v.y; s.z += v.z; s.w += v.w;
        }
        partial4[(size_t)blockIdx.x * (F_IN / 4) + c4] = s;
    }
}
__global__ __launch_bounds__(1024)
void k_reduce_agg(const float4* __restrict__ partial4, int nparts,
                  const float* __restrict__ W, float* __restrict__ agg) {
    __shared__ float4 lds[32][32];
    __shared__ float s[F_IN];
    __shared__ float aggLds[4][F_OUT];
    int t = threadIdx.x;
    int c4 = t & 31;
    int g  = t >> 5;
    {
        float4 acc = make_float4(0.f, 0.f, 0.f, 0.f);
        for (int b = g; b < nparts; b += 32) {
            float4 v = partial4[(size_t)b * (F_IN / 4) + c4];
            acc.x += v.x; acc.y += v.y; acc.z += v.z; acc.w += v.w;
        }
        lds[g][c4] = acc;
    }
    __syncthreads();
    for (int st = 16; st > 0; st >>= 1) {
        if (g < st) {
            float4 o = lds[g + st][c4];
            float4 v = lds[g][c4];
            v.x += o.x; v.y += o.y; v.z += o.z; v.w += o.w;
            lds[g][c4] = v;
        }
        __syncthreads();
    }
    if (g == 0) {
        float4 v = lds[0][c4];
        s[c4 * 4 + 0] = v.x; s[c4 * 4 + 1] = v.y;
        s[c4 * 4 + 2] = v.z; s[c4 * 4 + 3] = v.w;
    }
    __syncthreads();
    {
        int f  = t & 255;
        int kg = t >> 8;
        float acc = 0.f;
        #pragma unroll 8
        for (int k = kg * 32; k < kg * 32 + 32; ++k)
            acc += s[k] * W[(size_t)k * F_OUT + f];
        aggLds[kg][f] = acc;
    }
    __syncthreads();
    if (t < F_OUT)
        agg[t] = aggLds[0][t] + aggLds[1][t] + aggLds[2][t] + aggLds[3][t];
}
__global__ void k_outer(const float* __restrict__ dinv,
                        const float* __restrict__ agg,
                        const float* __restrict__ bias,
                        float4* __restrict__ out4, int n) {
    int i = blockIdx.x * blockDim.x + threadIdx.x;
    const int per_row = F_OUT / 4;
    int total = n * per_row;
    if (i >= total) return;
    int node = i >> 6;
    int f4   = i & 63;
    float d = dinv[node];
    float4 a  = ((const float4*)agg)[f4];
    float4 bb = ((const float4*)bias)[f4];
    float4 o;
    o.x = fmaf(d, a.x, bb.x);
    o.y = fmaf(d, a.y, bb.y);
    o.z = fmaf(d, a.z, bb.z);
    o.w = fmaf(d, a.w, bb.w);
    out4[i] = o;
}

// ---------------------------------------------------------------------------
static inline size_t align_up(size_t v, size_t a) { return (v + a - 1) & ~(a - 1); }

extern "C" void kernel_launch(void* const* d_in, const int* in_sizes, int n_in,
                              void* d_out, int out_size, void* d_ws, size_t ws_size,
                              hipStream_t stream) {
    const float* x    = (const float*)d_in[0];
    const int*   ei   = (const int*)  d_in[1];
    const float* W    = (const float*)d_in[2];
    const float* bias = (const float*)d_in[3];

    const int n = in_sizes[0] / F_IN;     // 12000
    const int E = in_sizes[1] / 2;        // 384000
    const int G = (n + 31) >> GBITS;      // 375
    const int C = (E + SBLK - 1) / SBLK;  // edges per scatter block (3000)
    const int rcap = (int)align_up((size_t)(2 * C), 64);  // region words (exact bound)

    char* ws = (char*)d_ws;
    size_t off_b = 0;
    float* dinv = (float*)(ws + off_b); off_b = align_up(off_b + (size_t)n * 4, 256);
    unsigned long long* sacc = (unsigned long long*)(ws + off_b);
    off_b = align_up(off_b + (size_t)F_IN * SACC_STRIDE * 8, 256);
    int* lofs_t = (int*)(ws + off_b); off_b = align_up(off_b + (size_t)(G + 1) * SBLK * 4, 256);
    unsigned* blockout = (unsigned*)(ws + off_b);
    size_t need = off_b + (size_t)SBLK * rcap * 4;

    bool fast = (G <= G_MAX) && (((n + 31) >> 5) <= WPR) && (n <= 65536) &&
                (2 * C <= STAGE_CAP) && (need <= ws_size);

    if (fast) {
        k_scatter_blockout<<<SBLK, STHR, 0, stream>>>(ei, E, G, lofs_t,
                                                      blockout, sacc, rcap);
        k_dedup_colsum<<<G, 256, 0, stream>>>(blockout, lofs_t, rcap,
                                              (const float4*)x, dinv, sacc,
                                              n, G);
        k_gemv_outer<<<304, 256, 0, stream>>>(sacc, W, bias, dinv,
                                              (float4*)d_out, n);
        return;
    }

    // ---- fallback: global-bitmap path ----
    const int row_words = (int)align_up((size_t)((n + 31) / 32), 64);
    const int NB = 512;
    size_t off_f = 0;
    float* dinv_f = (float*)(ws + off_f); off_f = align_up(off_f + (size_t)n * 4, 256);
    float* agg_f  = (float*)(ws + off_f); off_f = align_up(off_f + (size_t)F_OUT * 4, 256);
    float4* part_f = (float4*)(ws + off_f); off_f = align_up(off_f + (size_t)NB * F_IN * 4, 256);
    unsigned* bm = (unsigned*)(ws + off_f);
    size_t avail = (ws_size > off_f) ? (ws_size - off_f) : 0;
    long long fit = (long long)(avail / ((size_t)row_words * 4));
    int rows_per_chunk = (fit >= n) ? n : (fit > 0 ? (int)fit : 1);
    for (int r0 = 0; r0 < n; r0 += rows_per_chunk) {
        int rows = n - r0; if (rows > rows_per_chunk) rows = rows_per_chunk;
        size_t n4 = (size_t)rows * row_words / 4;
        int zgrid = (int)((n4 + 255) / 256); if (zgrid > 2048) zgrid = 2048;
        k_zero_simple<<<zgrid, 256, 0, stream>>>((float4*)bm, n4);
        k_set_bits_simple<<<(E + 255) / 256, 256, 0, stream>>>(ei, E, bm, r0, r0 + rows, row_words);
        k_degree_simple<<<(rows + 3) / 4, 256, 0, stream>>>(bm, dinv_f, r0, rows, row_words);
    }
    k_colsum_simple<<<NB, 256, 0, stream>>>((const float4*)x, dinv_f, part_f, n);
    k_reduce_agg<<<1, 1024, 0, stream>>>(part_f, NB, W, agg_f);
    int total4 = n * (F_OUT / 4);
    k_outer<<<(total4 + 255) / 256, 256, 0, stream>>>(dinv_f, agg_f, bias,
                                                      (float4*)d_out, n);
}

// Round 19
// 36.950 us; speedup vs baseline: 1.0045x; 1.0045x over previous
//
#include <hip/hip_runtime.h>
#include <math.h>

#define F_IN  128
#define F_OUT 256
#define GBITS 5            // 32 nodes per group
#define G_MAX 380          // max groups (G = ceil(n/32) = 375 for n=12000)
#define WPR   376          // padded words per LDS bitmap row (>= ceil(n/32))
#define SBLK  256          // scatter blocks (= dedup threads, 1 thread/run)
#define STHR  256          // scatter threads per block
#define STAGE_CAP 4096     // LDS staging items per scatter block (16 KB)

// ---------------------------------------------------------------------------
// S: block-region scatter (R17-verified logic, reshaped 256x256 so all 256
// CUs are occupied; scan = R9/R10-verified 2-elems-per-thread 512-wide
// Hillis-Steele). Fully deterministic addressing; NO global atomics, NO
// pre-zeroed memory, NO overflow (region capacity = 2*chunk, exact bound).
// Run content order race-permutes within a run; the per-run SET is exact and
// consumed via idempotent OR downstream => bitwise-deterministic.
// pack = node<<16 | other  (node < 65536 guaranteed by the fast gate).
// ---------------------------------------------------------------------------
__global__ __launch_bounds__(STHR)
void k_scatter_blockout(const int* __restrict__ ei, int E, int G,
                        int* __restrict__ lofs_t,        // [(G+1)][SBLK]
                        unsigned* __restrict__ blockout, // [SBLK][rcap]
                        int rcap) {
    __shared__ int hist[G_MAX];
    __shared__ int cur[G_MAX];
    __shared__ int sc[512];
    __shared__ unsigned stage[STAGE_CAP];          // 16 KB
    int b = blockIdx.x, t = threadIdx.x;

    for (int g = t; g < G; g += STHR) hist[g] = 0;
    __syncthreads();

    int C = (E + (int)gridDim.x - 1) / (int)gridDim.x;   // 1500
    int e0 = b * C, e1 = min(E, e0 + C);
    for (int e = e0 + t; e < e1; e += STHR) {
        int a = ei[e], c = ei[E + e];
        atomicAdd(&hist[a >> GBITS], 1);
        atomicAdd(&hist[c >> GBITS], 1);
    }
    __syncthreads();

    // 512-wide inclusive scan, 2 elements per thread (verified in R9/R10)
    int i1 = t + 256;
    int c0 = (t  < G) ? hist[t]  : 0;
    int c1 = (i1 < G) ? hist[i1] : 0;
    sc[t] = c0; sc[i1] = c1;
    __syncthreads();
    #pragma unroll
    for (int d = 1; d < 512; d <<= 1) {
        int v0 = (t  >= d) ? sc[t  - d] : 0;
        int v1 = (i1 >= d) ? sc[i1 - d] : 0;
        __syncthreads();
        sc[t] += v0; sc[i1] += v1;
        __syncthreads();
    }
    if (t < G) {
        int lo = sc[t] - c0;                       // exclusive prefix
        cur[t] = lo;
        lofs_t[(size_t)t * SBLK + b] = lo;
    }
    if (i1 < G) {
        int lo = sc[i1] - c1;
        cur[i1] = lo;
        lofs_t[(size_t)i1 * SBLK + b] = lo;
    }
    if (t == 0) lofs_t[(size_t)G * SBLK + b] = sc[511];
    __syncthreads();

    // counting-sort placement into LDS staging
    for (int e = e0 + t; e < e1; e += STHR) {
        int a = ei[e], c = ei[E + e];
        int s1 = atomicAdd(&cur[a >> GBITS], 1);
        stage[s1] = ((unsigned)a << 16) | (unsigned)c;
        int s2 = atomicAdd(&cur[c >> GBITS], 1);
        stage[s2] = ((unsigned)c << 16) | (unsigned)a;
    }
    __syncthreads();

    // contiguous, fully-coalesced copy-out to this block's region
    int tot = sc[511];
    unsigned* myout = blockout + (size_t)b * rcap;
    for (int s = t; s < tot; s += STHR)
        myout[s] = stage[s];
}

// ---------------------------------------------------------------------------
// D: per group of 32 nodes. Fetch = 256 short runs (1 thread per run, ~8
// items) located by lofs_t[g][b]..lofs_t[g+1][b] -> LDS bitmap with
// COUNT-ON-INSERT (all LDS atomics, no fences) -> dinv, then weighted
// colsum -> partial. Consumer phases byte-identical to R17's verified code.
// ---------------------------------------------------------------------------
union DedupLds {
    unsigned bm[32 * WPR];        // 48128 B (insert phase)
    float4   red[8][32];          // 4 KB   (colsum reduce; bm dead)
};

__global__ __launch_bounds__(256)
void k_dedup_colsum(const unsigned* __restrict__ blockout,
                    const int* __restrict__ lofs_t, int rcap,
                    const float4* __restrict__ x4,
                    float* __restrict__ dinv, float4* __restrict__ partial4,
                    int n, int G) {
    __shared__ DedupLds u;
    __shared__ int dcnt[32];
    __shared__ float dloc[32];
    int g = blockIdx.x, t = threadIdx.x;

    uint4* bm4 = (uint4*)u.bm;
    for (int i = t; i < (32 * WPR) / 4; i += 256)
        bm4[i] = make_uint4(0u, 0u, 0u, 0u);
    if (t < 32) dcnt[t] = 0;
    __syncthreads();

    // 1 thread per scatter-block run
    {
        int b = t;
        int lo = lofs_t[(size_t)g       * SBLK + b];
        int hi = lofs_t[(size_t)(g + 1) * SBLK + b];
        const unsigned* mo = blockout + (size_t)b * rcap;
        for (int i = lo; i < hi; ++i) {
            unsigned w = mo[i];
            unsigned lrow = (w >> 16) & 31u, col = w & 0xFFFFu;
            unsigned bit = 1u << (col & 31);
            unsigned old = atomicOr(&u.bm[lrow * WPR + (col >> 5)], bit);
            if (!(old & bit)) atomicAdd(&dcnt[lrow], 1);
        }
    }
    __syncthreads();

    if (t < 32) {
        float dv = 1.0f / sqrtf((float)dcnt[t]);   // deg==0 -> inf, matches ref
        dloc[t] = dv;
        int node = g * 32 + t;
        if (node < n) dinv[node] = dv;
    }
    __syncthreads();

    int c4 = t & 31, ro = t >> 5;         // ro 0..7
    float4 acc = make_float4(0.f, 0.f, 0.f, 0.f);
    for (int lr = ro; lr < 32; lr += 8) {
        int node = g * 32 + lr;
        if (node >= n) break;
        float dv = dloc[lr];
        float4 v = x4[(size_t)node * (F_IN / 4) + c4];
        acc.x += dv * v.x; acc.y += dv * v.y;
        acc.z += dv * v.z; acc.w += dv * v.w;
    }
    __syncthreads();                      // bm reads done; reuse LDS as scratch
    u.red[ro][c4] = acc;
    __syncthreads();
    if (ro == 0) {
        float4 s = u.red[0][c4];
        #pragma unroll
        for (int k = 1; k < 8; ++k) {
            float4 v = u.red[k][c4];
            s.x += v.x; s.y += v.y; s.z += v.z; s.w += v.w;
        }
        partial4[(size_t)g * (F_IN / 4) + c4] = s;
    }
}

// ---------------------------------------------------------------------------
// R: single 1024-thread block. Reduce partials -> s[128], then
// agg[f] = sum_k s[k]*W[k,f] with 4-way k-split. (R8/R12/R14/R17-verified.)
// ---------------------------------------------------------------------------
__global__ __launch_bounds__(1024)
void k_reduce_agg(const float4* __restrict__ partial4, int nparts,
                  const float* __restrict__ W, float* __restrict__ agg) {
    __shared__ float4 lds[32][32];
    __shared__ float s[F_IN];
    __shared__ float aggLds[4][F_OUT];
    int t = threadIdx.x;
    int c4 = t & 31;
    int g  = t >> 5;
    {
        float4 acc = make_float4(0.f, 0.f, 0.f, 0.f);
        for (int b = g; b < nparts; b += 32) {
            float4 v = partial4[(size_t)b * (F_IN / 4) + c4];
            acc.x += v.x; acc.y += v.y; acc.z += v.z; acc.w += v.w;
        }
        lds[g][c4] = acc;
    }
    __syncthreads();
    for (int st = 16; st > 0; st >>= 1) {
        if (g < st) {
            float4 o = lds[g + st][c4];
            float4 v = lds[g][c4];
            v.x += o.x; v.y += o.y; v.z += o.z; v.w += o.w;
            lds[g][c4] = v;
        }
        __syncthreads();
    }
    if (g == 0) {
        float4 v = lds[0][c4];
        s[c4 * 4 + 0] = v.x; s[c4 * 4 + 1] = v.y;
        s[c4 * 4 + 2] = v.z; s[c4 * 4 + 3] = v.w;
    }
    __syncthreads();
    {
        int f  = t & 255;
        int kg = t >> 8;
        float acc = 0.f;
        #pragma unroll 8
        for (int k = kg * 32; k < kg * 32 + 32; ++k)
            acc += s[k] * W[(size_t)k * F_OUT + f];
        aggLds[kg][f] = acc;
    }
    __syncthreads();
    if (t < F_OUT)
        agg[t] = aggLds[0][t] + aggLds[1][t] + aggLds[2][t] + aggLds[3][t];
}

// ---------------------------------------------------------------------------
// O: out[n,f] = dinv[n]*agg[f] + bias[f], float4-vectorized. (R8-verified.)
// ---------------------------------------------------------------------------
__global__ void k_outer(const float* __restrict__ dinv,
                        const float* __restrict__ agg,
                        const float* __restrict__ bias,
                        float4* __restrict__ out4, int n) {
    int i = blockIdx.x * blockDim.x + threadIdx.x;
    const int per_row = F_OUT / 4;
    int total = n * per_row;
    if (i >= total) return;
    int node = i >> 6;
    int f4   = i & 63;
    float d = dinv[node];
    float4 a  = ((const float4*)agg)[f4];
    float4 bb = ((const float4*)bias)[f4];
    float4 o;
    o.x = fmaf(d, a.x, bb.x);
    o.y = fmaf(d, a.y, bb.y);
    o.z = fmaf(d, a.z, bb.z);
    o.w = fmaf(d, a.w, bb.w);
    out4[i] = o;
}

// ===========================================================================
// Fallback (odd sizes / tiny workspace): round-4 global-bitmap path.
// ===========================================================================
__global__ __launch_bounds__(256)
void k_zero_simple(float4* __restrict__ p, size_t n4) {
    size_t i = (size_t)blockIdx.x * blockDim.x + threadIdx.x;
    size_t stride = (size_t)gridDim.x * blockDim.x;
    float4 z = make_float4(0.f, 0.f, 0.f, 0.f);
    for (; i < n4; i += stride) p[i] = z;
}
__global__ void k_set_bits_simple(const int* __restrict__ ei, int E,
                                  unsigned* __restrict__ bm, int r0, int r1,
                                  int row_words) {
    int e = blockIdx.x * blockDim.x + threadIdx.x;
    if (e >= E) return;
    int a = ei[e];
    int b = ei[E + e];
    if (a >= r0 && a < r1)
        atomicOr(&bm[(size_t)(a - r0) * row_words + (b >> 5)], 1u << (b & 31));
    if (b >= r0 && b < r1)
        atomicOr(&bm[(size_t)(b - r0) * row_words + (a >> 5)], 1u << (a & 31));
}
__global__ __launch_bounds__(256)
void k_degree_simple(const unsigned* __restrict__ bm, float* __restrict__ dinv,
                     int r0, int rows, int row_words) {
    int wave = threadIdx.x >> 6;
    int lane = threadIdx.x & 63;
    int row  = blockIdx.x * 4 + wave;
    if (row >= rows) return;
    const unsigned* p = bm + (size_t)row * row_words;
    int cnt = 0;
    for (int w = lane; w < row_words; w += 64)
        cnt += __popc(p[w]);
    #pragma unroll
    for (int off = 32; off > 0; off >>= 1)
        cnt += __shfl_down(cnt, off, 64);
    if (lane == 0)
        dinv[r0 + row] = 1.0f / sqrtf((float)cnt);
}
__global__ __launch_bounds__(256)
void k_colsum_simple(const float4* __restrict__ x4, const float* __restrict__ dinv,
                     float4* __restrict__ partial4, int n) {
    __shared__ float4 lds[8][32];
    int t = threadIdx.x;
    int c4 = t & 31;
    int ro = t >> 5;
    int rows_per = (n + (int)gridDim.x - 1) / (int)gridDim.x;
    int rbeg = blockIdx.x * rows_per;
    int rend = rbeg + rows_per; if (rend > n) rend = n;
    float4 acc = make_float4(0.f, 0.f, 0.f, 0.f);
    for (int r = rbeg + ro; r < rend; r += 8) {
        float dv = dinv[r];
        float4 v = x4[(size_t)r * (F_IN / 4) + c4];
        acc.x += dv * v.x; acc.y += dv * v.y;
        acc.z += dv * v.z; acc.w += dv * v.w;
    }
    lds[ro][c4] = acc;
    __syncthreads();
    if (ro == 0) {
        float4 s = lds[0][c4];
        #pragma unroll
        for (int g = 1; g < 8; ++g) {
            float4 v = lds[g][c4];
            s.x += v.x; s.y += v.y; s.z += v.z; s.w += v.w;
        }
        partial4[(size_t)blockIdx.x * (F_IN / 4) + c4] = s;
    }
}

// ---------------------------------------------------------------------------
static inline size_t align_up(size_t v, size_t a) { return (v + a - 1) & ~(a - 1); }

extern "C" void kernel_launch(void* const* d_in, const int* in_sizes, int n_in,
                              void* d_out, int out_size, void* d_ws, size_t ws_size,
                              hipStream_t stream) {
    const float* x    = (const float*)d_in[0];
    const int*   ei   = (const int*)  d_in[1];
    const float* W    = (const float*)d_in[2];
    const float* bias = (const float*)d_in[3];

    const int n = in_sizes[0] / F_IN;     // 12000
    const int E = in_sizes[1] / 2;        // 384000
    const int G = (n + 31) >> GBITS;      // 375
    const int C = (E + SBLK - 1) / SBLK;  // edges per scatter block (1500)
    const int rcap = (int)align_up((size_t)(2 * C), 64);  // region words (exact bound)

    char* ws = (char*)d_ws;
    size_t off_b = 0;
    float* dinv = (float*)(ws + off_b); off_b = align_up(off_b + (size_t)n * 4, 256);
    float* agg  = (float*)(ws + off_b); off_b = align_up(off_b + (size_t)F_OUT * 4, 256);
    float4* partial4 = (float4*)(ws + off_b); off_b = align_up(off_b + (size_t)G * F_IN * 4, 256);
    int* lofs_t = (int*)(ws + off_b); off_b = align_up(off_b + (size_t)(G + 1) * SBLK * 4, 256);
    unsigned* blockout = (unsigned*)(ws + off_b);
    size_t need = off_b + (size_t)SBLK * rcap * 4;

    bool fast = (G <= G_MAX) && (((n + 31) >> 5) <= WPR) && (n <= 65536) &&
                (2 * C <= STAGE_CAP) && (need <= ws_size);

    if (fast) {
        k_scatter_blockout<<<SBLK, STHR, 0, stream>>>(ei, E, G, lofs_t,
                                                      blockout, rcap);
        k_dedup_colsum<<<G, 256, 0, stream>>>(blockout, lofs_t, rcap,
                                              (const float4*)x, dinv, partial4,
                                              n, G);
        k_reduce_agg<<<1, 1024, 0, stream>>>(partial4, G, W, agg);
        int total4 = n * (F_OUT / 4);
        k_outer<<<(total4 + 255) / 256, 256, 0, stream>>>(dinv, agg, bias,
                                                          (float4*)d_out, n);
        return;
    }

    // ---- fallback: global-bitmap path ----
    const int row_words = (int)align_up((size_t)((n + 31) / 32), 64);
    const int NB = 512;
    size_t off_f = 0;
    float* dinv_f = (float*)(ws + off_f); off_f = align_up(off_f + (size_t)n * 4, 256);
    float* agg_f  = (float*)(ws + off_f); off_f = align_up(off_f + (size_t)F_OUT * 4, 256);
    float4* part_f = (float4*)(ws + off_f); off_f = align_up(off_f + (size_t)NB * F_IN * 4, 256);
    unsigned* bm = (unsigned*)(ws + off_f);
    size_t avail = (ws_size > off_f) ? (ws_size - off_f) : 0;
    long long fit = (long long)(avail / ((size_t)row_words * 4));
    int rows_per_chunk = (fit >= n) ? n : (fit > 0 ? (int)fit : 1);
    for (int r0 = 0; r0 < n; r0 += rows_per_chunk) {
        int rows = n - r0; if (rows > rows_per_chunk) rows = rows_per_chunk;
        size_t n4 = (size_t)rows * row_words / 4;
        int zgrid = (int)((n4 + 255) / 256); if (zgrid > 2048) zgrid = 2048;
        k_zero_simple<<<zgrid, 256, 0, stream>>>((float4*)bm, n4);
        k_set_bits_simple<<<(E + 255) / 256, 256, 0, stream>>>(ei, E, bm, r0, r0 + rows, row_words);
        k_degree_simple<<<(rows + 3) / 4, 256, 0, stream>>>(bm, dinv_f, r0, rows, row_words);
    }
    k_colsum_simple<<<NB, 256, 0, stream>>>((const float4*)x, dinv_f, part_f, n);
    k_reduce_agg<<<1, 1024, 0, stream>>>(part_f, NB, W, agg_f);
    int total4 = n * (F_OUT / 4);
    k_outer<<<(total4 + 255) / 256, 256, 0, stream>>>(dinv_f, agg_f, bias,
                                                      (float4*)d_out, n);
}

// Round 20
// 32.334 us; speedup vs baseline: 1.1479x; 1.1428x over previous
//
#include <hip/hip_runtime.h>
#include <math.h>

#define F_IN  128
#define F_OUT 256
#define GBITS 5            // 32 nodes per group
#define G_MAX 380          // max groups (G = ceil(n/32) = 375 for n=12000)
#define WPR   376          // padded words per LDS bitmap row (>= ceil(n/32))
#define SBLK  128          // scatter blocks (dedup uses 2 threads/run -> 256)
#define STHR  512          // scatter threads per block
#define STAGE_CAP 8192     // LDS staging items per scatter block (32 KB)
#define NSLOT 8            // atomic fan-out slots per s[k]
#define LINE8 8            // ULL per 64B line
#define SCALE 4294967296.0 // 2^32 fixed-point scale

// ---------------------------------------------------------------------------
// S: block-region scatter (R17-verified, byte-identical logic). Block 0
// additionally zeroes sacc (64 KB; visible to dedup via kernel boundary).
// ---------------------------------------------------------------------------
__global__ __launch_bounds__(STHR)
void k_scatter_blockout(const int* __restrict__ ei, int E, int G,
                        int* __restrict__ lofs_t,        // [(G+1)][SBLK]
                        unsigned* __restrict__ blockout, // [SBLK][rcap]
                        unsigned long long* __restrict__ sacc, // [F_IN*NSLOT*LINE8]
                        int rcap) {
    __shared__ int hist[G_MAX];
    __shared__ int cur[G_MAX];
    __shared__ int sc[STHR];
    __shared__ unsigned stage[STAGE_CAP];          // 32 KB
    int b = blockIdx.x, t = threadIdx.x;

    if (b == 0) {
        for (int i = t; i < F_IN * NSLOT; i += STHR)
            sacc[(size_t)i * LINE8] = 0ull;
    }

    for (int g = t; g < G; g += STHR) hist[g] = 0;
    __syncthreads();

    int C = (E + (int)gridDim.x - 1) / (int)gridDim.x;
    int e0 = b * C, e1 = min(E, e0 + C);
    for (int e = e0 + t; e < e1; e += STHR) {
        int a = ei[e], c = ei[E + e];
        atomicAdd(&hist[a >> GBITS], 1);
        atomicAdd(&hist[c >> GBITS], 1);
    }
    __syncthreads();

    sc[t] = (t < G) ? hist[t] : 0;
    __syncthreads();
    #pragma unroll
    for (int d = 1; d < STHR; d <<= 1) {
        int v = (t >= d) ? sc[t - d] : 0;
        __syncthreads();
        sc[t] += v;
        __syncthreads();
    }
    if (t < G) {
        int lo = sc[t] - hist[t];                  // exclusive prefix
        cur[t] = lo;
        lofs_t[(size_t)t * SBLK + b] = lo;
    }
    if (t == 0) lofs_t[(size_t)G * SBLK + b] = sc[STHR - 1];
    __syncthreads();

    for (int e = e0 + t; e < e1; e += STHR) {
        int a = ei[e], c = ei[E + e];
        int s1 = atomicAdd(&cur[a >> GBITS], 1);
        stage[s1] = ((unsigned)a << 16) | (unsigned)c;
        int s2 = atomicAdd(&cur[c >> GBITS], 1);
        stage[s2] = ((unsigned)c << 16) | (unsigned)a;
    }
    __syncthreads();

    int tot = sc[STHR - 1];
    unsigned* myout = blockout + (size_t)b * rcap;
    for (int s = t; s < tot; s += STHR)
        myout[s] = stage[s];
}

// ---------------------------------------------------------------------------
// D: per group of 32 nodes (insert/count/colsum phases byte-identical to
// R17's verified kernel). The block's colsum partial (fixed-order float
// tree) is committed via int64 fixed-point atomicAdd with 8-WAY SLOT
// FAN-OUT (slot = g&7, each (k,slot) on its own 64B line): 47 RMWs/line
// instead of R18's 375 -> serialization ~1.2 us. Integer adds are
// order-invariant => bitwise-deterministic. No fences.
// ---------------------------------------------------------------------------
union DedupLds {
    unsigned bm[32 * WPR];        // 48128 B (insert phase)
    float4   red[8][32];          // 4 KB   (colsum reduce; bm dead)
};

__global__ __launch_bounds__(256)
void k_dedup_colsum(const unsigned* __restrict__ blockout,
                    const int* __restrict__ lofs_t, int rcap,
                    const float4* __restrict__ x4,
                    float* __restrict__ dinv,
                    unsigned long long* __restrict__ sacc,
                    int n, int G) {
    __shared__ DedupLds u;
    __shared__ int dcnt[32];
    __shared__ float dloc[32];
    int g = blockIdx.x, t = threadIdx.x;

    uint4* bm4 = (uint4*)u.bm;
    for (int i = t; i < (32 * WPR) / 4; i += 256)
        bm4[i] = make_uint4(0u, 0u, 0u, 0u);
    if (t < 32) dcnt[t] = 0;
    __syncthreads();

    {
        int b = t >> 1, half = t & 1;
        int lo = lofs_t[(size_t)g       * SBLK + b];
        int hi = lofs_t[(size_t)(g + 1) * SBLK + b];
        const unsigned* mo = blockout + (size_t)b * rcap;
        for (int i = lo + half; i < hi; i += 2) {
            unsigned w = mo[i];
            unsigned lrow = (w >> 16) & 31u, col = w & 0xFFFFu;
            unsigned bit = 1u << (col & 31);
            unsigned old = atomicOr(&u.bm[lrow * WPR + (col >> 5)], bit);
            if (!(old & bit)) atomicAdd(&dcnt[lrow], 1);
        }
    }
    __syncthreads();

    if (t < 32) {
        float dv = 1.0f / sqrtf((float)dcnt[t]);   // deg==0 -> inf, matches ref
        dloc[t] = dv;
        int node = g * 32 + t;
        if (node < n) dinv[node] = dv;
    }
    __syncthreads();

    int c4 = t & 31, ro = t >> 5;         // ro 0..7
    float4 acc = make_float4(0.f, 0.f, 0.f, 0.f);
    for (int lr = ro; lr < 32; lr += 8) {
        int node = g * 32 + lr;
        if (node >= n) break;
        float dv = dloc[lr];
        float4 v = x4[(size_t)node * (F_IN / 4) + c4];
        acc.x += dv * v.x; acc.y += dv * v.y;
        acc.z += dv * v.z; acc.w += dv * v.w;
    }
    __syncthreads();                      // bm reads done; reuse LDS as scratch
    u.red[ro][c4] = acc;
    __syncthreads();
    if (ro == 0) {
        float4 s = u.red[0][c4];
        #pragma unroll
        for (int k = 1; k < 8; ++k) {
            float4 v = u.red[k][c4];
            s.x += v.x; s.y += v.y; s.z += v.z; s.w += v.w;
        }
        int slot = g & (NSLOT - 1);
        atomicAdd(&sacc[((size_t)((c4 * 4 + 0) * NSLOT + slot)) * LINE8],
                  (unsigned long long)(long long)llrint((double)s.x * SCALE));
        atomicAdd(&sacc[((size_t)((c4 * 4 + 1) * NSLOT + slot)) * LINE8],
                  (unsigned long long)(long long)llrint((double)s.y * SCALE));
        atomicAdd(&sacc[((size_t)((c4 * 4 + 2) * NSLOT + slot)) * LINE8],
                  (unsigned long long)(long long)llrint((double)s.z * SCALE));
        atomicAdd(&sacc[((size_t)((c4 * 4 + 3) * NSLOT + slot)) * LINE8],
                  (unsigned long long)(long long)llrint((double)s.w * SCALE));
    }
}

// ---------------------------------------------------------------------------
// O (fused): per block — decode s (exact int64 sum of 8 slots, then scale),
// GEMV agg = s·W (thread t owns column t, coalesced W reads, shared via
// LDS), then grid-stride output: out[n,f] = dinv[n]*agg[f] + bias[f].
// ---------------------------------------------------------------------------
__global__ __launch_bounds__(256)
void k_gemv_outer(const unsigned long long* __restrict__ sacc,
                  const float* __restrict__ W, const float* __restrict__ bias,
                  const float* __restrict__ dinv,
                  float4* __restrict__ out4, int n) {
    __shared__ float s[F_IN];
    __shared__ __align__(16) float aggL[F_OUT];
    int t = threadIdx.x;
    if (t < F_IN) {
        long long v = 0;
        #pragma unroll
        for (int j = 0; j < NSLOT; ++j)
            v += (long long)sacc[((size_t)(t * NSLOT + j)) * LINE8];
        s[t] = (float)((double)v * (1.0 / SCALE));
    }
    __syncthreads();

    {   // thread t -> output column t (coalesced W row reads)
        float a = 0.f;
        #pragma unroll 8
        for (int k = 0; k < F_IN; ++k)
            a = fmaf(s[k], W[(size_t)k * F_OUT + t], a);
        aggL[t] = a;
    }
    __syncthreads();

    int f4 = t & 63;                      // invariant: grid stride % 64 == 0
    float4 ag = ((const float4*)aggL)[f4];
    float4 b4 = ((const float4*)bias)[f4];
    int total4 = n * (F_OUT / 4);
    int gs = (int)gridDim.x * 256;
    for (int i = (int)blockIdx.x * 256 + t; i < total4; i += gs) {
        float d = dinv[i >> 6];           // 64 consecutive lanes share node
        float4 o;
        o.x = fmaf(d, ag.x, b4.x);
        o.y = fmaf(d, ag.y, b4.y);
        o.z = fmaf(d, ag.z, b4.z);
        o.w = fmaf(d, ag.w, b4.w);
        out4[i] = o;
    }
}

// ===========================================================================
// Fallback (odd sizes / tiny workspace): round-4 global-bitmap path.
// ===========================================================================
__global__ __launch_bounds__(256)
void k_zero_simple(float4* __restrict__ p, size_t n4) {
    size_t i = (size_t)blockIdx.x * blockDim.x + threadIdx.x;
    size_t stride = (size_t)gridDim.x * blockDim.x;
    float4 z = make_float4(0.f, 0.f, 0.f, 0.f);
    for (; i < n4; i += stride) p[i] = z;
}
__global__ void k_set_bits_simple(const int* __restrict__ ei, int E,
                                  unsigned* __restrict__ bm, int r0, int r1,
                                  int row_words) {
    int e = blockIdx.x * blockDim.x + threadIdx.x;
    if (e >= E) return;
    int a = ei[e];
    int b = ei[E + e];
    if (a >= r0 && a < r1)
        atomicOr(&bm[(size_t)(a - r0) * row_words + (b >> 5)], 1u << (b & 31));
    if (b >= r0 && b < r1)
        atomicOr(&bm[(size_t)(b - r0) * row_words + (a >> 5)], 1u << (a & 31));
}
__global__ __launch_bounds__(256)
void k_degree_simple(const unsigned* __restrict__ bm, float* __restrict__ dinv,
                     int r0, int rows, int row_words) {
    int wave = threadIdx.x >> 6;
    int lane = threadIdx.x & 63;
    int row  = blockIdx.x * 4 + wave;
    if (row >= rows) return;
    const unsigned* p = bm + (size_t)row * row_words;
    int cnt = 0;
    for (int w = lane; w < row_words; w += 64)
        cnt += __popc(p[w]);
    #pragma unroll
    for (int off = 32; off > 0; off >>= 1)
        cnt += __shfl_down(cnt, off, 64);
    if (lane == 0)
        dinv[r0 + row] = 1.0f / sqrtf((float)cnt);
}
__global__ __launch_bounds__(256)
void k_colsum_simple(const float4* __restrict__ x4, const float* __restrict__ dinv,
                     float4* __restrict__ partial4, int n) {
    __shared__ float4 lds[8][32];
    int t = threadIdx.x;
    int c4 = t & 31;
    int ro = t >> 5;
    int rows_per = (n + (int)gridDim.x - 1) / (int)gridDim.x;
    int rbeg = blockIdx.x * rows_per;
    int rend = rbeg + rows_per; if (rend > n) rend = n;
    float4 acc = make_float4(0.f, 0.f, 0.f, 0.f);
    for (int r = rbeg + ro; r < rend; r += 8) {
        float dv = dinv[r];
        float4 v = x4[(size_t)r * (F_IN / 4) + c4];
        acc.x += dv * v.x; acc.y += dv * v.y;
        acc.z += dv * v.z; acc.w += dv * v.w;
    }
    lds[ro][c4] = acc;
    __syncthreads();
    if (ro == 0) {
        float4 s = lds[0][c4];
        #pragma unroll
        for (int g = 1; g < 8; ++g) {
            float4 v = lds[g][c4];
            s.x += v.x; s.y += v.y; s.z += v.z; s.w += v.w;
        }
        partial4[(size_t)blockIdx.x * (F_IN / 4) + c4] = s;
    }
}
__global__ __launch_bounds__(1024)
void k_reduce_agg(const float4* __restrict__ partial4, int nparts,
                  const float* __restrict__ W, float* __restrict__ agg) {
    __shared__ float4 lds[32][32];
    __shared__ float s[F_IN];
    __shared__ float aggLds[4][F_OUT];
    int t = threadIdx.x;
    int c4 = t & 31;
    int g  = t >> 5;
    {
        float4 acc = make_float4(0.f, 0.f, 0.f, 0.f);
        for (int b = g; b < nparts; b += 32) {
            float4 v = partial4[(size_t)b * (F_IN / 4) + c4];
            acc.x += v.x; acc.y += v.y; acc.z += v.z; acc.w += v.w;
        }
        lds[g][c4] = acc;
    }
    __syncthreads();
    for (int st = 16; st > 0; st >>= 1) {
        if (g < st) {
            float4 o = lds[g + st][c4];
            float4 v = lds[g][c4];
            v.x += o.x; v.y += o.y; v.z += o.z; v.w += o.w;
            lds[g][c4] = v;
        }
        __syncthreads();
    }
    if (g == 0) {
        float4 v = lds[0][c4];
        s[c4 * 4 + 0] = v.x; s[c4 * 4 + 1] = v.y;
        s[c4 * 4 + 2] = v.z; s[c4 * 4 + 3] = v.w;
    }
    __syncthreads();
    {
        int f  = t & 255;
        int kg = t >> 8;
        float acc = 0.f;
        #pragma unroll 8
        for (int k = kg * 32; k < kg * 32 + 32; ++k)
            acc += s[k] * W[(size_t)k * F_OUT + f];
        aggLds[kg][f] = acc;
    }
    __syncthreads();
    if (t < F_OUT)
        agg[t] = aggLds[0][t] + aggLds[1][t] + aggLds[2][t] + aggLds[3][t];
}
__global__ void k_outer(const float* __restrict__ dinv,
                        const float* __restrict__ agg,
                        const float* __restrict__ bias,
                        float4* __restrict__ out4, int n) {
    int i = blockIdx.x * blockDim.x + threadIdx.x;
    const int per_row = F_OUT / 4;
    int total = n * per_row;
    if (i >= total) return;
    int node = i >> 6;
    int f4   = i & 63;
    float d = dinv[node];
    float4 a  = ((const float4*)agg)[f4];
    float4 bb = ((const float4*)bias)[f4];
    float4 o;
    o.x = fmaf(d, a.x, bb.x);
    o.y = fmaf(d, a.y, bb.y);
    o.z = fmaf(d, a.z, bb.z);
    o.w = fmaf(d, a.w, bb.w);
    out4[i] = o;
}

// ---------------------------------------------------------------------------
static inline size_t align_up(size_t v, size_t a) { return (v + a - 1) & ~(a - 1); }

extern "C" void kernel_launch(void* const* d_in, const int* in_sizes, int n_in,
                              void* d_out, int out_size, void* d_ws, size_t ws_size,
                              hipStream_t stream) {
    const float* x    = (const float*)d_in[0];
    const int*   ei   = (const int*)  d_in[1];
    const float* W    = (const float*)d_in[2];
    const float* bias = (const float*)d_in[3];

    const int n = in_sizes[0] / F_IN;     // 12000
    const int E = in_sizes[1] / 2;        // 384000
    const int G = (n + 31) >> GBITS;      // 375
    const int C = (E + SBLK - 1) / SBLK;  // edges per scatter block (3000)
    const int rcap = (int)align_up((size_t)(2 * C), 64);  // region words (exact bound)

    char* ws = (char*)d_ws;
    size_t off_b = 0;
    float* dinv = (float*)(ws + off_b); off_b = align_up(off_b + (size_t)n * 4, 256);
    unsigned long long* sacc = (unsigned long long*)(ws + off_b);
    off_b = align_up(off_b + (size_t)F_IN * NSLOT * LINE8 * 8, 256);   // 64 KB
    int* lofs_t = (int*)(ws + off_b); off_b = align_up(off_b + (size_t)(G + 1) * SBLK * 4, 256);
    unsigned* blockout = (unsigned*)(ws + off_b);
    size_t need = off_b + (size_t)SBLK * rcap * 4;

    bool fast = (G <= G_MAX) && (((n + 31) >> 5) <= WPR) && (n <= 65536) &&
                (2 * C <= STAGE_CAP) && (need <= ws_size);

    if (fast) {
        k_scatter_blockout<<<SBLK, STHR, 0, stream>>>(ei, E, G, lofs_t,
                                                      blockout, sacc, rcap);
        k_dedup_colsum<<<G, 256, 0, stream>>>(blockout, lofs_t, rcap,
                                              (const float4*)x, dinv, sacc,
                                              n, G);
        k_gemv_outer<<<304, 256, 0, stream>>>(sacc, W, bias, dinv,
                                              (float4*)d_out, n);
        return;
    }

    // ---- fallback: global-bitmap path ----
    const int row_words = (int)align_up((size_t)((n + 31) / 32), 64);
    const int NB = 512;
    size_t off_f = 0;
    float* dinv_f = (float*)(ws + off_f); off_f = align_up(off_f + (size_t)n * 4, 256);
    float* agg_f  = (float*)(ws + off_f); off_f = align_up(off_f + (size_t)F_OUT * 4, 256);
    float4* part_f = (float4*)(ws + off_f); off_f = align_up(off_f + (size_t)NB * F_IN * 4, 256);
    unsigned* bm = (unsigned*)(ws + off_f);
    size_t avail = (ws_size > off_f) ? (ws_size - off_f) : 0;
    long long fit = (long long)(avail / ((size_t)row_words * 4));
    int rows_per_chunk = (fit >= n) ? n : (fit > 0 ? (int)fit : 1);
    for (int r0 = 0; r0 < n; r0 += rows_per_chunk) {
        int rows = n - r0; if (rows > rows_per_chunk) rows = rows_per_chunk;
        size_t n4 = (size_t)rows * row_words / 4;
        int zgrid = (int)((n4 + 255) / 256); if (zgrid > 2048) zgrid = 2048;
        k_zero_simple<<<zgrid, 256, 0, stream>>>((float4*)bm, n4);
        k_set_bits_simple<<<(E + 255) / 256, 256, 0, stream>>>(ei, E, bm, r0, r0 + rows, row_words);
        k_degree_simple<<<(rows + 3) / 4, 256, 0, stream>>>(bm, dinv_f, r0, rows, row_words);
    }
    k_colsum_simple<<<NB, 256, 0, stream>>>((const float4*)x, dinv_f, part_f, n);
    k_reduce_agg<<<1, 1024, 0, stream>>>(part_f, NB, W, agg_f);
    int total4 = n * (F_OUT / 4);
    k_outer<<<(total4 + 255) / 256, 256, 0, stream>>>(dinv_f, agg_f, bias,
                                                      (float4*)d_out, n);
}

// Round 21
// 31.178 us; speedup vs baseline: 1.1905x; 1.0371x over previous
//
#include <hip/hip_runtime.h>
#include <math.h>

#define F_IN  128
#define F_OUT 256
#define GBITS 5            // 32 nodes per group
#define G_MAX 380          // max groups (G = ceil(n/32) = 375 for n=12000)
#define WPR   376          // padded words per LDS bitmap row (>= ceil(n/32))
#define SBLK  128          // scatter blocks (dedup uses 2 threads/run -> 256)
#define STHR  512          // scatter threads per block
#define STAGE_CAP 8192     // LDS staging items per scatter block (32 KB)
#define NSLOT 8            // atomic fan-out slots per s[k]
#define LINE8 8            // ULL per 64B line
#define SCALE 4294967296.0 // 2^32 fixed-point scale

// ---------------------------------------------------------------------------
// S: block-region scatter (R17/R20-verified logic). Scan replaced by
// wave-level __shfl_up scan: 2 barriers instead of 18 (latency win; all
// 128 blocks co-resident so barriers are pure critical-path cost).
// Block 0 zeroes sacc (visible to dedup via kernel boundary).
// ---------------------------------------------------------------------------
__global__ __launch_bounds__(STHR)
void k_scatter_blockout(const int* __restrict__ ei, int E, int G,
                        int* __restrict__ lofs_t,        // [(G+1)][SBLK]
                        unsigned* __restrict__ blockout, // [SBLK][rcap]
                        unsigned long long* __restrict__ sacc, // [F_IN*NSLOT*LINE8]
                        int rcap) {
    __shared__ int hist[G_MAX];
    __shared__ int cur[G_MAX];
    __shared__ int wsum[8];
    __shared__ int tot;
    __shared__ unsigned stage[STAGE_CAP];          // 32 KB
    int b = blockIdx.x, t = threadIdx.x;

    if (b == 0) {
        for (int i = t; i < F_IN * NSLOT; i += STHR)
            sacc[(size_t)i * LINE8] = 0ull;
    }

    for (int g = t; g < G; g += STHR) hist[g] = 0;
    __syncthreads();

    int C = (E + (int)gridDim.x - 1) / (int)gridDim.x;
    int e0 = b * C, e1 = min(E, e0 + C);
    for (int e = e0 + t; e < e1; e += STHR) {
        int a = ei[e], c = ei[E + e];
        atomicAdd(&hist[a >> GBITS], 1);
        atomicAdd(&hist[c >> GBITS], 1);
    }
    __syncthreads();

    // ---- wave-level inclusive scan over 512 slots (2 barriers total) ----
    int lane = t & 63, wid = t >> 6;
    int v = (t < G) ? hist[t] : 0;
    int scv = v;
    #pragma unroll
    for (int d = 1; d < 64; d <<= 1) {
        int o = __shfl_up(scv, d, 64);
        if (lane >= d) scv += o;
    }
    if (lane == 63) wsum[wid] = scv;
    __syncthreads();
    if (t < 8) {
        int w = wsum[t];
        #pragma unroll
        for (int d = 1; d < 8; d <<= 1) {
            int o = __shfl_up(w, d, 8);
            if ((t & 7) >= d) w += o;
        }
        wsum[t] = w;                              // inclusive wave totals
        if (t == 7) tot = w;
    }
    __syncthreads();
    int incl = scv + (wid > 0 ? wsum[wid - 1] : 0);
    if (t < G) {
        int lo = incl - v;                        // exclusive prefix
        cur[t] = lo;
        lofs_t[(size_t)t * SBLK + b] = lo;
    }
    if (t == 0) lofs_t[(size_t)G * SBLK + b] = tot;
    __syncthreads();

    // counting-sort placement into LDS staging
    for (int e = e0 + t; e < e1; e += STHR) {
        int a = ei[e], c = ei[E + e];
        int s1 = atomicAdd(&cur[a >> GBITS], 1);
        stage[s1] = ((unsigned)a << 16) | (unsigned)c;
        int s2 = atomicAdd(&cur[c >> GBITS], 1);
        stage[s2] = ((unsigned)c << 16) | (unsigned)a;
    }
    __syncthreads();

    // contiguous, fully-coalesced copy-out to this block's region
    int total = tot;
    unsigned* myout = blockout + (size_t)b * rcap;
    for (int s = t; s < total; s += STHR)
        myout[s] = stage[s];
}

// ---------------------------------------------------------------------------
// D: per group of 32 nodes (insert/count/commit byte-identical to R20's
// verified kernel). x-loads ISSUED BEFORE the insert loop (T14 issue-early:
// ~500cy HBM latency hides under the LDS-atomic insert chain).
// ---------------------------------------------------------------------------
union DedupLds {
    unsigned bm[32 * WPR];        // 48128 B (insert phase)
    float4   red[8][32];          // 4 KB   (colsum reduce; bm dead)
};

__global__ __launch_bounds__(256)
void k_dedup_colsum(const unsigned* __restrict__ blockout,
                    const int* __restrict__ lofs_t, int rcap,
                    const float4* __restrict__ x4,
                    float* __restrict__ dinv,
                    unsigned long long* __restrict__ sacc,
                    int n, int G) {
    __shared__ DedupLds u;
    __shared__ int dcnt[32];
    __shared__ float dloc[32];
    int g = blockIdx.x, t = threadIdx.x;

    // issue-early x prefetch (consumed after insert; guards below keep
    // padded rows out of the accumulate so inf*0 never occurs)
    int c4 = t & 31, ro = t >> 5;                 // ro 0..7
    float4 xv[4];
    #pragma unroll
    for (int k = 0; k < 4; ++k) {
        int node = g * 32 + ro + k * 8;
        xv[k] = (node < n) ? x4[(size_t)node * (F_IN / 4) + c4]
                           : make_float4(0.f, 0.f, 0.f, 0.f);
    }

    uint4* bm4 = (uint4*)u.bm;
    for (int i = t; i < (32 * WPR) / 4; i += 256)
        bm4[i] = make_uint4(0u, 0u, 0u, 0u);
    if (t < 32) dcnt[t] = 0;
    __syncthreads();

    {
        int b = t >> 1, half = t & 1;
        int lo = lofs_t[(size_t)g       * SBLK + b];
        int hi = lofs_t[(size_t)(g + 1) * SBLK + b];
        const unsigned* mo = blockout + (size_t)b * rcap;
        for (int i = lo + half; i < hi; i += 2) {
            unsigned w = mo[i];
            unsigned lrow = (w >> 16) & 31u, col = w & 0xFFFFu;
            unsigned bit = 1u << (col & 31);
            unsigned old = atomicOr(&u.bm[lrow * WPR + (col >> 5)], bit);
            if (!(old & bit)) atomicAdd(&dcnt[lrow], 1);
        }
    }
    __syncthreads();

    if (t < 32) {
        float dv = 1.0f / sqrtf((float)dcnt[t]);   // deg==0 -> inf, matches ref
        dloc[t] = dv;
        int node = g * 32 + t;
        if (node < n) dinv[node] = dv;
    }
    __syncthreads();

    float4 acc = make_float4(0.f, 0.f, 0.f, 0.f);
    #pragma unroll
    for (int k = 0; k < 4; ++k) {
        int node = g * 32 + ro + k * 8;
        if (node < n) {
            float dv = dloc[ro + k * 8];
            acc.x += dv * xv[k].x; acc.y += dv * xv[k].y;
            acc.z += dv * xv[k].z; acc.w += dv * xv[k].w;
        }
    }
    __syncthreads();                      // bm reads done; reuse LDS as scratch
    u.red[ro][c4] = acc;
    __syncthreads();
    // fixed 2-level tree over ro (0..7) then commit, same order as R20:
    if (ro == 0) {
        float4 s = u.red[0][c4];
        #pragma unroll
        for (int k = 1; k < 8; ++k) {
            float4 vv = u.red[k][c4];
            s.x += vv.x; s.y += vv.y; s.z += vv.z; s.w += vv.w;
        }
        int slot = g & (NSLOT - 1);
        atomicAdd(&sacc[((size_t)((c4 * 4 + 0) * NSLOT + slot)) * LINE8],
                  (unsigned long long)(long long)llrint((double)s.x * SCALE));
        atomicAdd(&sacc[((size_t)((c4 * 4 + 1) * NSLOT + slot)) * LINE8],
                  (unsigned long long)(long long)llrint((double)s.y * SCALE));
        atomicAdd(&sacc[((size_t)((c4 * 4 + 2) * NSLOT + slot)) * LINE8],
                  (unsigned long long)(long long)llrint((double)s.z * SCALE));
        atomicAdd(&sacc[((size_t)((c4 * 4 + 3) * NSLOT + slot)) * LINE8],
                  (unsigned long long)(long long)llrint((double)s.w * SCALE));
    }
}

// ---------------------------------------------------------------------------
// O (fused): decode s (exact int64 sum of 8 slots), GEMV agg = s·W,
// grid-stride output. (R20-verified.)
// ---------------------------------------------------------------------------
__global__ __launch_bounds__(256)
void k_gemv_outer(const unsigned long long* __restrict__ sacc,
                  const float* __restrict__ W, const float* __restrict__ bias,
                  const float* __restrict__ dinv,
                  float4* __restrict__ out4, int n) {
    __shared__ float s[F_IN];
    __shared__ __align__(16) float aggL[F_OUT];
    int t = threadIdx.x;
    if (t < F_IN) {
        long long v = 0;
        #pragma unroll
        for (int j = 0; j < NSLOT; ++j)
            v += (long long)sacc[((size_t)(t * NSLOT + j)) * LINE8];
        s[t] = (float)((double)v * (1.0 / SCALE));
    }
    __syncthreads();

    {
        float a = 0.f;
        #pragma unroll 8
        for (int k = 0; k < F_IN; ++k)
            a = fmaf(s[k], W[(size_t)k * F_OUT + t], a);
        aggL[t] = a;
    }
    __syncthreads();

    int f4 = t & 63;                      // invariant: grid stride % 64 == 0
    float4 ag = ((const float4*)aggL)[f4];
    float4 b4 = ((const float4*)bias)[f4];
    int total4 = n * (F_OUT / 4);
    int gs = (int)gridDim.x * 256;
    for (int i = (int)blockIdx.x * 256 + t; i < total4; i += gs) {
        float d = dinv[i >> 6];           // 64 consecutive lanes share node
        float4 o;
        o.x = fmaf(d, ag.x, b4.x);
        o.y = fmaf(d, ag.y, b4.y);
        o.z = fmaf(d, ag.z, b4.z);
        o.w = fmaf(d, ag.w, b4.w);
        out4[i] = o;
    }
}

// ===========================================================================
// Fallback (odd sizes / tiny workspace): round-4 global-bitmap path.
// ===========================================================================
__global__ __launch_bounds__(256)
void k_zero_simple(float4* __restrict__ p, size_t n4) {
    size_t i = (size_t)blockIdx.x * blockDim.x + threadIdx.x;
    size_t stride = (size_t)gridDim.x * blockDim.x;
    float4 z = make_float4(0.f, 0.f, 0.f, 0.f);
    for (; i < n4; i += stride) p[i] = z;
}
__global__ void k_set_bits_simple(const int* __restrict__ ei, int E,
                                  unsigned* __restrict__ bm, int r0, int r1,
                                  int row_words) {
    int e = blockIdx.x * blockDim.x + threadIdx.x;
    if (e >= E) return;
    int a = ei[e];
    int b = ei[E + e];
    if (a >= r0 && a < r1)
        atomicOr(&bm[(size_t)(a - r0) * row_words + (b >> 5)], 1u << (b & 31));
    if (b >= r0 && b < r1)
        atomicOr(&bm[(size_t)(b - r0) * row_words + (a >> 5)], 1u << (a & 31));
}
__global__ __launch_bounds__(256)
void k_degree_simple(const unsigned* __restrict__ bm, float* __restrict__ dinv,
                     int r0, int rows, int row_words) {
    int wave = threadIdx.x >> 6;
    int lane = threadIdx.x & 63;
    int row  = blockIdx.x * 4 + wave;
    if (row >= rows) return;
    const unsigned* p = bm + (size_t)row * row_words;
    int cnt = 0;
    for (int w = lane; w < row_words; w += 64)
        cnt += __popc(p[w]);
    #pragma unroll
    for (int off = 32; off > 0; off >>= 1)
        cnt += __shfl_down(cnt, off, 64);
    if (lane == 0)
        dinv[r0 + row] = 1.0f / sqrtf((float)cnt);
}
__global__ __launch_bounds__(256)
void k_colsum_simple(const float4* __restrict__ x4, const float* __restrict__ dinv,
                     float4* __restrict__ partial4, int n) {
    __shared__ float4 lds[8][32];
    int t = threadIdx.x;
    int c4 = t & 31;
    int ro = t >> 5;
    int rows_per = (n + (int)gridDim.x - 1) / (int)gridDim.x;
    int rbeg = blockIdx.x * rows_per;
    int rend = rbeg + rows_per; if (rend > n) rend = n;
    float4 acc = make_float4(0.f, 0.f, 0.f, 0.f);
    for (int r = rbeg + ro; r < rend; r += 8) {
        float dv = dinv[r];
        float4 v = x4[(size_t)r * (F_IN / 4) + c4];
        acc.x += dv * v.x; acc.y += dv * v.y;
        acc.z += dv * v.z; acc.w += dv * v.w;
    }
    lds[ro][c4] = acc;
    __syncthreads();
    if (ro == 0) {
        float4 s = lds[0][c4];
        #pragma unroll
        for (int g = 1; g < 8; ++g) {
            float4 v = lds[g][c4];
            s.x += v.x; s.y += v.y; s.z += v.z; s.w += v.w;
        }
        partial4[(size_t)blockIdx.x * (F_IN / 4) + c4] = s;
    }
}
__global__ __launch_bounds__(1024)
void k_reduce_agg(const float4* __restrict__ partial4, int nparts,
                  const float* __restrict__ W, float* __restrict__ agg) {
    __shared__ float4 lds[32][32];
    __shared__ float s[F_IN];
    __shared__ float aggLds[4][F_OUT];
    int t = threadIdx.x;
    int c4 = t & 31;
    int g  = t >> 5;
    {
        float4 acc = make_float4(0.f, 0.f, 0.f, 0.f);
        for (int b = g; b < nparts; b += 32) {
            float4 v = partial4[(size_t)b * (F_IN / 4) + c4];
            acc.x += v.x; acc.y += v.y; acc.z += v.z; acc.w += v.w;
        }
        lds[g][c4] = acc;
    }
    __syncthreads();
    for (int st = 16; st > 0; st >>= 1) {
        if (g < st) {
            float4 o = lds[g + st][c4];
            float4 v = lds[g][c4];
            v.x += o.x; v.y += o.y; v.z += o.z; v.w += o.w;
            lds[g][c4] = v;
        }
        __syncthreads();
    }
    if (g == 0) {
        float4 v = lds[0][c4];
        s[c4 * 4 + 0] = v.x; s[c4 * 4 + 1] = v.y;
        s[c4 * 4 + 2] = v.z; s[c4 * 4 + 3] = v.w;
    }
    __syncthreads();
    {
        int f  = t & 255;
        int kg = t >> 8;
        float acc = 0.f;
        #pragma unroll 8
        for (int k = kg * 32; k < kg * 32 + 32; ++k)
            acc += s[k] * W[(size_t)k * F_OUT + f];
        aggLds[kg][f] = acc;
    }
    __syncthreads();
    if (t < F_OUT)
        agg[t] = aggLds[0][t] + aggLds[1][t] + aggLds[2][t] + aggLds[3][t];
}
__global__ void k_outer(const float* __restrict__ dinv,
                        const float* __restrict__ agg,
                        const float* __restrict__ bias,
                        float4* __restrict__ out4, int n) {
    int i = blockIdx.x * blockDim.x + threadIdx.x;
    const int per_row = F_OUT / 4;
    int total = n * per_row;
    if (i >= total) return;
    int node = i >> 6;
    int f4   = i & 63;
    float d = dinv[node];
    float4 a  = ((const float4*)agg)[f4];
    float4 bb = ((const float4*)bias)[f4];
    float4 o;
    o.x = fmaf(d, a.x, bb.x);
    o.y = fmaf(d, a.y, bb.y);
    o.z = fmaf(d, a.z, bb.z);
    o.w = fmaf(d, a.w, bb.w);
    out4[i] = o;
}

// ---------------------------------------------------------------------------
static inline size_t align_up(size_t v, size_t a) { return (v + a - 1) & ~(a - 1); }

extern "C" void kernel_launch(void* const* d_in, const int* in_sizes, int n_in,
                              void* d_out, int out_size, void* d_ws, size_t ws_size,
                              hipStream_t stream) {
    const float* x    = (const float*)d_in[0];
    const int*   ei   = (const int*)  d_in[1];
    const float* W    = (const float*)d_in[2];
    const float* bias = (const float*)d_in[3];

    const int n = in_sizes[0] / F_IN;     // 12000
    const int E = in_sizes[1] / 2;        // 384000
    const int G = (n + 31) >> GBITS;      // 375
    const int C = (E + SBLK - 1) / SBLK;  // edges per scatter block (3000)
    const int rcap = (int)align_up((size_t)(2 * C), 64);  // region words (exact bound)

    char* ws = (char*)d_ws;
    size_t off_b = 0;
    float* dinv = (float*)(ws + off_b); off_b = align_up(off_b + (size_t)n * 4, 256);
    unsigned long long* sacc = (unsigned long long*)(ws + off_b);
    off_b = align_up(off_b + (size_t)F_IN * NSLOT * LINE8 * 8, 256);   // 64 KB
    int* lofs_t = (int*)(ws + off_b); off_b = align_up(off_b + (size_t)(G + 1) * SBLK * 4, 256);
    unsigned* blockout = (unsigned*)(ws + off_b);
    size_t need = off_b + (size_t)SBLK * rcap * 4;

    bool fast = (G <= G_MAX) && (((n + 31) >> 5) <= WPR) && (n <= 65536) &&
                (2 * C <= STAGE_CAP) && (need <= ws_size);

    if (fast) {
        k_scatter_blockout<<<SBLK, STHR, 0, stream>>>(ei, E, G, lofs_t,
                                                      blockout, sacc, rcap);
        k_dedup_colsum<<<G, 256, 0, stream>>>(blockout, lofs_t, rcap,
                                              (const float4*)x, dinv, sacc,
                                              n, G);
        k_gemv_outer<<<304, 256, 0, stream>>>(sacc, W, bias, dinv,
                                              (float4*)d_out, n);
        return;
    }

    // ---- fallback: global-bitmap path ----
    const int row_words = (int)align_up((size_t)((n + 31) / 32), 64);
    const int NB = 512;
    size_t off_f = 0;
    float* dinv_f = (float*)(ws + off_f); off_f = align_up(off_f + (size_t)n * 4, 256);
    float* agg_f  = (float*)(ws + off_f); off_f = align_up(off_f + (size_t)F_OUT * 4, 256);
    float4* part_f = (float4*)(ws + off_f); off_f = align_up(off_f + (size_t)NB * F_IN * 4, 256);
    unsigned* bm = (unsigned*)(ws + off_f);
    size_t avail = (ws_size > off_f) ? (ws_size - off_f) : 0;
    long long fit = (long long)(avail / ((size_t)row_words * 4));
    int rows_per_chunk = (fit >= n) ? n : (fit > 0 ? (int)fit : 1);
    for (int r0 = 0; r0 < n; r0 += rows_per_chunk) {
        int rows = n - r0; if (rows > rows_per_chunk) rows = rows_per_chunk;
        size_t n4 = (size_t)rows * row_words / 4;
        int zgrid = (int)((n4 + 255) / 256); if (zgrid > 2048) zgrid = 2048;
        k_zero_simple<<<zgrid, 256, 0, stream>>>((float4*)bm, n4);
        k_set_bits_simple<<<(E + 255) / 256, 256, 0, stream>>>(ei, E, bm, r0, r0 + rows, row_words);
        k_degree_simple<<<(rows + 3) / 4, 256, 0, stream>>>(bm, dinv_f, r0, rows, row_words);
    }
    k_colsum_simple<<<NB, 256, 0, stream>>>((const float4*)x, dinv_f, part_f, n);
    k_reduce_agg<<<1, 1024, 0, stream>>>(part_f, NB, W, agg_f);
    int total4 = n * (F_OUT / 4);
    k_outer<<<(total4 + 255) / 256, 256, 0, stream>>>(dinv_f, agg_f, bias,
                                                      (float4*)d_out, n);
}

// Round 22
// 29.828 us; speedup vs baseline: 1.2443x; 1.0453x over previous
//
#include <hip/hip_runtime.h>
#include <math.h>

#define F_IN  128
#define F_OUT 256
#define GBITS 5            // 32 nodes per group
#define G_MAX 380          // max groups (G = ceil(n/32) = 375 for n=12000)
#define WPR   376          // padded words per LDS bitmap row (>= ceil(n/32))
#define SBLK  128          // scatter blocks (dedup uses 4 threads/run -> 512)
#define STHR  512          // scatter threads per block
#define STAGE_CAP 8192     // LDS staging items per scatter block (32 KB)
#define NSLOT 8            // atomic fan-out slots per s[k]
#define LINE8 8            // ULL per 64B line
#define SCALE 4294967296.0 // 2^32 fixed-point scale

// ---------------------------------------------------------------------------
// S: block-region scatter (R21-verified: shuffle-scan, 2 barriers).
// Block 0 zeroes sacc (visible to dedup via kernel boundary).
// ---------------------------------------------------------------------------
__global__ __launch_bounds__(STHR)
void k_scatter_blockout(const int* __restrict__ ei, int E, int G,
                        int* __restrict__ lofs_t,        // [(G+1)][SBLK]
                        unsigned* __restrict__ blockout, // [SBLK][rcap]
                        unsigned long long* __restrict__ sacc, // [F_IN*NSLOT*LINE8]
                        int rcap) {
    __shared__ int hist[G_MAX];
    __shared__ int cur[G_MAX];
    __shared__ int wsum[8];
    __shared__ int tot;
    __shared__ unsigned stage[STAGE_CAP];          // 32 KB
    int b = blockIdx.x, t = threadIdx.x;

    if (b == 0) {
        for (int i = t; i < F_IN * NSLOT; i += STHR)
            sacc[(size_t)i * LINE8] = 0ull;
    }

    for (int g = t; g < G; g += STHR) hist[g] = 0;
    __syncthreads();

    int C = (E + (int)gridDim.x - 1) / (int)gridDim.x;
    int e0 = b * C, e1 = min(E, e0 + C);
    for (int e = e0 + t; e < e1; e += STHR) {
        int a = ei[e], c = ei[E + e];
        atomicAdd(&hist[a >> GBITS], 1);
        atomicAdd(&hist[c >> GBITS], 1);
    }
    __syncthreads();

    // wave-level inclusive scan over 512 slots (2 barriers total)
    int lane = t & 63, wid = t >> 6;
    int v = (t < G) ? hist[t] : 0;
    int scv = v;
    #pragma unroll
    for (int d = 1; d < 64; d <<= 1) {
        int o = __shfl_up(scv, d, 64);
        if (lane >= d) scv += o;
    }
    if (lane == 63) wsum[wid] = scv;
    __syncthreads();
    if (t < 8) {
        int w = wsum[t];
        #pragma unroll
        for (int d = 1; d < 8; d <<= 1) {
            int o = __shfl_up(w, d, 8);
            if ((t & 7) >= d) w += o;
        }
        wsum[t] = w;
        if (t == 7) tot = w;
    }
    __syncthreads();
    int incl = scv + (wid > 0 ? wsum[wid - 1] : 0);
    if (t < G) {
        int lo = incl - v;                        // exclusive prefix
        cur[t] = lo;
        lofs_t[(size_t)t * SBLK + b] = lo;
    }
    if (t == 0) lofs_t[(size_t)G * SBLK + b] = tot;
    __syncthreads();

    for (int e = e0 + t; e < e1; e += STHR) {
        int a = ei[e], c = ei[E + e];
        int s1 = atomicAdd(&cur[a >> GBITS], 1);
        stage[s1] = ((unsigned)a << 16) | (unsigned)c;
        int s2 = atomicAdd(&cur[c >> GBITS], 1);
        stage[s2] = ((unsigned)c << 16) | (unsigned)a;
    }
    __syncthreads();

    int total = tot;
    unsigned* myout = blockout + (size_t)b * rcap;
    for (int s = t; s < total; s += STHR)
        myout[s] = stage[s];
}

// ---------------------------------------------------------------------------
// D: 512 threads (was 256) — halves every per-thread chain at no occupancy
// cost (48.5 KB LDS caps at 3 blocks/CU either way; 375 blocks co-resident).
// Zero: 23 uint4/thread. Insert: 4 threads/run, ~4 chained LDS atomics.
// Colsum: 2 rows/thread, 16-deep fixed LDS tree (order-fixed => determin.).
// Commit (fan-out int64 fixed-point) byte-identical to R20/R21-verified.
// ---------------------------------------------------------------------------
union DedupLds {
    unsigned bm[32 * WPR];        // 48128 B (insert phase)
    float4   red[16][32];         // 8 KB   (colsum reduce; bm dead)
};

__global__ __launch_bounds__(512)
void k_dedup_colsum(const unsigned* __restrict__ blockout,
                    const int* __restrict__ lofs_t, int rcap,
                    const float4* __restrict__ x4,
                    float* __restrict__ dinv,
                    unsigned long long* __restrict__ sacc,
                    int n, int G) {
    __shared__ DedupLds u;
    __shared__ int dcnt[32];
    __shared__ float dloc[32];
    int g = blockIdx.x, t = threadIdx.x;

    // issue-early x prefetch: 2 rows per thread (rows ro and ro+16)
    int c4 = t & 31, ro = t >> 5;                 // ro 0..15
    float4 xv[2];
    #pragma unroll
    for (int k = 0; k < 2; ++k) {
        int node = g * 32 + ro + k * 16;
        xv[k] = (node < n) ? x4[(size_t)node * (F_IN / 4) + c4]
                           : make_float4(0.f, 0.f, 0.f, 0.f);
    }

    uint4* bm4 = (uint4*)u.bm;
    for (int i = t; i < (32 * WPR) / 4; i += 512)
        bm4[i] = make_uint4(0u, 0u, 0u, 0u);
    if (t < 32) dcnt[t] = 0;
    __syncthreads();

    {
        int b = t >> 2, q = t & 3;                // 4 threads per run
        int lo = lofs_t[(size_t)g       * SBLK + b];
        int hi = lofs_t[(size_t)(g + 1) * SBLK + b];
        const unsigned* mo = blockout + (size_t)b * rcap;
        for (int i = lo + q; i < hi; i += 4) {
            unsigned w = mo[i];
            unsigned lrow = (w >> 16) & 31u, col = w & 0xFFFFu;
            unsigned bit = 1u << (col & 31);
            unsigned old = atomicOr(&u.bm[lrow * WPR + (col >> 5)], bit);
            if (!(old & bit)) atomicAdd(&dcnt[lrow], 1);
        }
    }
    __syncthreads();

    if (t < 32) {
        float dv = 1.0f / sqrtf((float)dcnt[t]);   // deg==0 -> inf, matches ref
        dloc[t] = dv;
        int node = g * 32 + t;
        if (node < n) dinv[node] = dv;
    }
    __syncthreads();

    float4 acc = make_float4(0.f, 0.f, 0.f, 0.f);
    #pragma unroll
    for (int k = 0; k < 2; ++k) {
        int node = g * 32 + ro + k * 16;
        if (node < n) {
            float dv = dloc[ro + k * 16];
            acc.x += dv * xv[k].x; acc.y += dv * xv[k].y;
            acc.z += dv * xv[k].z; acc.w += dv * xv[k].w;
        }
    }
    __syncthreads();                      // bm reads done; reuse LDS as scratch
    u.red[ro][c4] = acc;
    __syncthreads();
    if (ro == 0) {
        float4 s = u.red[0][c4];
        #pragma unroll
        for (int k = 1; k < 16; ++k) {
            float4 vv = u.red[k][c4];
            s.x += vv.x; s.y += vv.y; s.z += vv.z; s.w += vv.w;
        }
        int slot = g & (NSLOT - 1);
        atomicAdd(&sacc[((size_t)((c4 * 4 + 0) * NSLOT + slot)) * LINE8],
                  (unsigned long long)(long long)llrint((double)s.x * SCALE));
        atomicAdd(&sacc[((size_t)((c4 * 4 + 1) * NSLOT + slot)) * LINE8],
                  (unsigned long long)(long long)llrint((double)s.y * SCALE));
        atomicAdd(&sacc[((size_t)((c4 * 4 + 2) * NSLOT + slot)) * LINE8],
                  (unsigned long long)(long long)llrint((double)s.z * SCALE));
        atomicAdd(&sacc[((size_t)((c4 * 4 + 3) * NSLOT + slot)) * LINE8],
                  (unsigned long long)(long long)llrint((double)s.w * SCALE));
    }
}

// ---------------------------------------------------------------------------
// O (fused): decode s (exact int64 sum of 8 slots), GEMV agg = s·W,
// grid-stride output. (R20/R21-verified.)
// ---------------------------------------------------------------------------
__global__ __launch_bounds__(256)
void k_gemv_outer(const unsigned long long* __restrict__ sacc,
                  const float* __restrict__ W, const float* __restrict__ bias,
                  const float* __restrict__ dinv,
                  float4* __restrict__ out4, int n) {
    __shared__ float s[F_IN];
    __shared__ __align__(16) float aggL[F_OUT];
    int t = threadIdx.x;
    if (t < F_IN) {
        long long v = 0;
        #pragma unroll
        for (int j = 0; j < NSLOT; ++j)
            v += (long long)sacc[((size_t)(t * NSLOT + j)) * LINE8];
        s[t] = (float)((double)v * (1.0 / SCALE));
    }
    __syncthreads();

    {
        float a = 0.f;
        #pragma unroll 8
        for (int k = 0; k < F_IN; ++k)
            a = fmaf(s[k], W[(size_t)k * F_OUT + t], a);
        aggL[t] = a;
    }
    __syncthreads();

    int f4 = t & 63;                      // invariant: grid stride % 64 == 0
    float4 ag = ((const float4*)aggL)[f4];
    float4 b4 = ((const float4*)bias)[f4];
    int total4 = n * (F_OUT / 4);
    int gs = (int)gridDim.x * 256;
    for (int i = (int)blockIdx.x * 256 + t; i < total4; i += gs) {
        float d = dinv[i >> 6];           // 64 consecutive lanes share node
        float4 o;
        o.x = fmaf(d, ag.x, b4.x);
        o.y = fmaf(d, ag.y, b4.y);
        o.z = fmaf(d, ag.z, b4.z);
        o.w = fmaf(d, ag.w, b4.w);
        out4[i] = o;
    }
}

// ===========================================================================
// Fallback (odd sizes / tiny workspace): round-4 global-bitmap path.
// ===========================================================================
__global__ __launch_bounds__(256)
void k_zero_simple(float4* __restrict__ p, size_t n4) {
    size_t i = (size_t)blockIdx.x * blockDim.x + threadIdx.x;
    size_t stride = (size_t)gridDim.x * blockDim.x;
    float4 z = make_float4(0.f, 0.f, 0.f, 0.f);
    for (; i < n4; i += stride) p[i] = z;
}
__global__ void k_set_bits_simple(const int* __restrict__ ei, int E,
                                  unsigned* __restrict__ bm, int r0, int r1,
                                  int row_words) {
    int e = blockIdx.x * blockDim.x + threadIdx.x;
    if (e >= E) return;
    int a = ei[e];
    int b = ei[E + e];
    if (a >= r0 && a < r1)
        atomicOr(&bm[(size_t)(a - r0) * row_words + (b >> 5)], 1u << (b & 31));
    if (b >= r0 && b < r1)
        atomicOr(&bm[(size_t)(b - r0) * row_words + (a >> 5)], 1u << (a & 31));
}
__global__ __launch_bounds__(256)
void k_degree_simple(const unsigned* __restrict__ bm, float* __restrict__ dinv,
                     int r0, int rows, int row_words) {
    int wave = threadIdx.x >> 6;
    int lane = threadIdx.x & 63;
    int row  = blockIdx.x * 4 + wave;
    if (row >= rows) return;
    const unsigned* p = bm + (size_t)row * row_words;
    int cnt = 0;
    for (int w = lane; w < row_words; w += 64)
        cnt += __popc(p[w]);
    #pragma unroll
    for (int off = 32; off > 0; off >>= 1)
        cnt += __shfl_down(cnt, off, 64);
    if (lane == 0)
        dinv[r0 + row] = 1.0f / sqrtf((float)cnt);
}
__global__ __launch_bounds__(256)
void k_colsum_simple(const float4* __restrict__ x4, const float* __restrict__ dinv,
                     float4* __restrict__ partial4, int n) {
    __shared__ float4 lds[8][32];
    int t = threadIdx.x;
    int c4 = t & 31;
    int ro = t >> 5;
    int rows_per = (n + (int)gridDim.x - 1) / (int)gridDim.x;
    int rbeg = blockIdx.x * rows_per;
    int rend = rbeg + rows_per; if (rend > n) rend = n;
    float4 acc = make_float4(0.f, 0.f, 0.f, 0.f);
    for (int r = rbeg + ro; r < rend; r += 8) {
        float dv = dinv[r];
        float4 v = x4[(size_t)r * (F_IN / 4) + c4];
        acc.x += dv * v.x; acc.y += dv * v.y;
        acc.z += dv * v.z; acc.w += dv * v.w;
    }
    lds[ro][c4] = acc;
    __syncthreads();
    if (ro == 0) {
        float4 s = lds[0][c4];
        #pragma unroll
        for (int g = 1; g < 8; ++g) {
            float4 v = lds[g][c4];
            s.x += v.x; s.y += v.y; s.z += v.z; s.w += v.w;
        }
        partial4[(size_t)blockIdx.x * (F_IN / 4) + c4] = s;
    }
}
__global__ __launch_bounds__(1024)
void k_reduce_agg(const float4* __restrict__ partial4, int nparts,
                  const float* __restrict__ W, float* __restrict__ agg) {
    __shared__ float4 lds[32][32];
    __shared__ float s[F_IN];
    __shared__ float aggLds[4][F_OUT];
    int t = threadIdx.x;
    int c4 = t & 31;
    int g  = t >> 5;
    {
        float4 acc = make_float4(0.f, 0.f, 0.f, 0.f);
        for (int b = g; b < nparts; b += 32) {
            float4 v = partial4[(size_t)b * (F_IN / 4) + c4];
            acc.x += v.x; acc.y += v.y; acc.z += v.z; acc.w += v.w;
        }
        lds[g][c4] = acc;
    }
    __syncthreads();
    for (int st = 16; st > 0; st >>= 1) {
        if (g < st) {
            float4 o = lds[g + st][c4];
            float4 v = lds[g][c4];
            v.x += o.x; v.y += o.y; v.z += o.z; v.w += o.w;
            lds[g][c4] = v;
        }
        __syncthreads();
    }
    if (g == 0) {
        float4 v = lds[0][c4];
        s[c4 * 4 + 0] = v.x; s[c4 * 4 + 1] = v.y;
        s[c4 * 4 + 2] = v.z; s[c4 * 4 + 3] = v.w;
    }
    __syncthreads();
    {
        int f  = t & 255;
        int kg = t >> 8;
        float acc = 0.f;
        #pragma unroll 8
        for (int k = kg * 32; k < kg * 32 + 32; ++k)
            acc += s[k] * W[(size_t)k * F_OUT + f];
        aggLds[kg][f] = acc;
    }
    __syncthreads();
    if (t < F_OUT)
        agg[t] = aggLds[0][t] + aggLds[1][t] + aggLds[2][t] + aggLds[3][t];
}
__global__ void k_outer(const float* __restrict__ dinv,
                        const float* __restrict__ agg,
                        const float* __restrict__ bias,
                        float4* __restrict__ out4, int n) {
    int i = blockIdx.x * blockDim.x + threadIdx.x;
    const int per_row = F_OUT / 4;
    int total = n * per_row;
    if (i >= total) return;
    int node = i >> 6;
    int f4   = i & 63;
    float d = dinv[node];
    float4 a  = ((const float4*)agg)[f4];
    float4 bb = ((const float4*)bias)[f4];
    float4 o;
    o.x = fmaf(d, a.x, bb.x);
    o.y = fmaf(d, a.y, bb.y);
    o.z = fmaf(d, a.z, bb.z);
    o.w = fmaf(d, a.w, bb.w);
    out4[i] = o;
}

// ---------------------------------------------------------------------------
static inline size_t align_up(size_t v, size_t a) { return (v + a - 1) & ~(a - 1); }

extern "C" void kernel_launch(void* const* d_in, const int* in_sizes, int n_in,
                              void* d_out, int out_size, void* d_ws, size_t ws_size,
                              hipStream_t stream) {
    const float* x    = (const float*)d_in[0];
    const int*   ei   = (const int*)  d_in[1];
    const float* W    = (const float*)d_in[2];
    const float* bias = (const float*)d_in[3];

    const int n = in_sizes[0] / F_IN;     // 12000
    const int E = in_sizes[1] / 2;        // 384000
    const int G = (n + 31) >> GBITS;      // 375
    const int C = (E + SBLK - 1) / SBLK;  // edges per scatter block (3000)
    const int rcap = (int)align_up((size_t)(2 * C), 64);  // region words (exact bound)

    char* ws = (char*)d_ws;
    size_t off_b = 0;
    float* dinv = (float*)(ws + off_b); off_b = align_up(off_b + (size_t)n * 4, 256);
    unsigned long long* sacc = (unsigned long long*)(ws + off_b);
    off_b = align_up(off_b + (size_t)F_IN * NSLOT * LINE8 * 8, 256);   // 64 KB
    int* lofs_t = (int*)(ws + off_b); off_b = align_up(off_b + (size_t)(G + 1) * SBLK * 4, 256);
    unsigned* blockout = (unsigned*)(ws + off_b);
    size_t need = off_b + (size_t)SBLK * rcap * 4;

    bool fast = (G <= G_MAX) && (((n + 31) >> 5) <= WPR) && (n <= 65536) &&
                (2 * C <= STAGE_CAP) && (need <= ws_size);

    if (fast) {
        k_scatter_blockout<<<SBLK, STHR, 0, stream>>>(ei, E, G, lofs_t,
                                                      blockout, sacc, rcap);
        k_dedup_colsum<<<G, 512, 0, stream>>>(blockout, lofs_t, rcap,
                                              (const float4*)x, dinv, sacc,
                                              n, G);
        k_gemv_outer<<<304, 256, 0, stream>>>(sacc, W, bias, dinv,
                                              (float4*)d_out, n);
        return;
    }

    // ---- fallback: global-bitmap path ----
    const int row_words = (int)align_up((size_t)((n + 31) / 32), 64);
    const int NB = 512;
    size_t off_f = 0;
    float* dinv_f = (float*)(ws + off_f); off_f = align_up(off_f + (size_t)n * 4, 256);
    float* agg_f  = (float*)(ws + off_f); off_f = align_up(off_f + (size_t)F_OUT * 4, 256);
    float4* part_f = (float4*)(ws + off_f); off_f = align_up(off_f + (size_t)NB * F_IN * 4, 256);
    unsigned* bm = (unsigned*)(ws + off_f);
    size_t avail = (ws_size > off_f) ? (ws_size - off_f) : 0;
    long long fit = (long long)(avail / ((size_t)row_words * 4));
    int rows_per_chunk = (fit >= n) ? n : (fit > 0 ? (int)fit : 1);
    for (int r0 = 0; r0 < n; r0 += rows_per_chunk) {
        int rows = n - r0; if (rows > rows_per_chunk) rows = rows_per_chunk;
        size_t n4 = (size_t)rows * row_words / 4;
        int zgrid = (int)((n4 + 255) / 256); if (zgrid > 2048) zgrid = 2048;
        k_zero_simple<<<zgrid, 256, 0, stream>>>((float4*)bm, n4);
        k_set_bits_simple<<<(E + 255) / 256, 256, 0, stream>>>(ei, E, bm, r0, r0 + rows, row_words);
        k_degree_simple<<<(rows + 3) / 4, 256, 0, stream>>>(bm, dinv_f, r0, rows, row_words);
    }
    k_colsum_simple<<<NB, 256, 0, stream>>>((const float4*)x, dinv_f, part_f, n);
    k_reduce_agg<<<1, 1024, 0, stream>>>(part_f, NB, W, agg_f);
    int total4 = n * (F_OUT / 4);
    k_outer<<<(total4 + 255) / 256, 256, 0, stream>>>(dinv_f, agg_f, bias,
                                                      (float4*)d_out, n);
}

// Round 23
// 29.704 us; speedup vs baseline: 1.2495x; 1.0042x over previous
//
#include <hip/hip_runtime.h>
#include <math.h>

#define F_IN  128
#define F_OUT 256
#define GBITS 5            // 32 nodes per group
#define G_MAX 380          // max groups (G = ceil(n/32) = 375 for n=12000)
#define WPR   376          // padded words per LDS bitmap row (>= ceil(n/32))
#define SBLK  128          // scatter blocks (dedup uses 4 threads/run -> 512)
#define STHR  512          // scatter threads per block
#define EPT   8            // max edges per scatter thread (C <= EPT*STHR gate)
#define STAGE_CAP 8192     // LDS staging items per scatter block (32 KB)
#define NSLOT 8            // atomic fan-out slots per s[k]
#define LINE8 8            // ULL per 64B line
#define SCALE 4294967296.0 // 2^32 fixed-point scale

// ---------------------------------------------------------------------------
// S: block-region scatter (R21/R22-verified structure). Edge values cached
// in REGISTERS during the histogram pass (fixed-8 unrolled loop, compile-
// time indices) so the placement pass reads no global memory at all.
// Block 0 zeroes sacc (visible to dedup via kernel boundary).
// ---------------------------------------------------------------------------
__global__ __launch_bounds__(STHR)
void k_scatter_blockout(const int* __restrict__ ei, int E, int G,
                        int* __restrict__ lofs_t,        // [(G+1)][SBLK]
                        unsigned* __restrict__ blockout, // [SBLK][rcap]
                        unsigned long long* __restrict__ sacc, // [F_IN*NSLOT*LINE8]
                        int rcap) {
    __shared__ int hist[G_MAX];
    __shared__ int cur[G_MAX];
    __shared__ int wsum[8];
    __shared__ int tot;
    __shared__ unsigned stage[STAGE_CAP];          // 32 KB
    int b = blockIdx.x, t = threadIdx.x;

    if (b == 0) {
        for (int i = t; i < F_IN * NSLOT; i += STHR)
            sacc[(size_t)i * LINE8] = 0ull;
    }

    for (int g = t; g < G; g += STHR) hist[g] = 0;
    __syncthreads();

    int C = (E + (int)gridDim.x - 1) / (int)gridDim.x;
    int e0 = b * C, e1 = min(E, e0 + C);

    // histogram pass + register-cache the edges (fixed unroll => regs)
    int ea[EPT], eb[EPT];
    #pragma unroll
    for (int k = 0; k < EPT; ++k) {
        int e = e0 + t + k * STHR;
        bool ok = e < e1;
        int a = ok ? ei[e]     : -1;
        int c = ok ? ei[E + e] : -1;
        ea[k] = a; eb[k] = c;
        if (ok) {
            atomicAdd(&hist[a >> GBITS], 1);
            atomicAdd(&hist[c >> GBITS], 1);
        }
    }
    __syncthreads();

    // wave-level inclusive scan over 512 slots (2 barriers total)
    int lane = t & 63, wid = t >> 6;
    int v = (t < G) ? hist[t] : 0;
    int scv = v;
    #pragma unroll
    for (int d = 1; d < 64; d <<= 1) {
        int o = __shfl_up(scv, d, 64);
        if (lane >= d) scv += o;
    }
    if (lane == 63) wsum[wid] = scv;
    __syncthreads();
    if (t < 8) {
        int w = wsum[t];
        #pragma unroll
        for (int d = 1; d < 8; d <<= 1) {
            int o = __shfl_up(w, d, 8);
            if ((t & 7) >= d) w += o;
        }
        wsum[t] = w;
        if (t == 7) tot = w;
    }
    __syncthreads();
    int incl = scv + (wid > 0 ? wsum[wid - 1] : 0);
    if (t < G) {
        int lo = incl - v;                        // exclusive prefix
        cur[t] = lo;
        lofs_t[(size_t)t * SBLK + b] = lo;
    }
    if (t == 0) lofs_t[(size_t)G * SBLK + b] = tot;
    __syncthreads();

    // placement pass: registers only (no global reads)
    #pragma unroll
    for (int k = 0; k < EPT; ++k) {
        int a = ea[k];
        if (a >= 0) {
            int c = eb[k];
            int s1 = atomicAdd(&cur[a >> GBITS], 1);
            stage[s1] = ((unsigned)a << 16) | (unsigned)c;
            int s2 = atomicAdd(&cur[c >> GBITS], 1);
            stage[s2] = ((unsigned)c << 16) | (unsigned)a;
        }
    }
    __syncthreads();

    int total = tot;
    unsigned* myout = blockout + (size_t)b * rcap;
    for (int s = t; s < total; s += STHR)
        myout[s] = stage[s];
}

// ---------------------------------------------------------------------------
// D: 512-thread dedup (R22-verified). Insert: 4 threads/run; colsum: 2 rows/
// thread, 16-deep fixed LDS tree; commit: int64 fixed-point fan-out.
// ---------------------------------------------------------------------------
union DedupLds {
    unsigned bm[32 * WPR];        // 48128 B (insert phase)
    float4   red[16][32];         // 8 KB   (colsum reduce; bm dead)
};

__global__ __launch_bounds__(512)
void k_dedup_colsum(const unsigned* __restrict__ blockout,
                    const int* __restrict__ lofs_t, int rcap,
                    const float4* __restrict__ x4,
                    float* __restrict__ dinv,
                    unsigned long long* __restrict__ sacc,
                    int n, int G) {
    __shared__ DedupLds u;
    __shared__ int dcnt[32];
    __shared__ float dloc[32];
    int g = blockIdx.x, t = threadIdx.x;

    // issue-early x prefetch: 2 rows per thread (rows ro and ro+16)
    int c4 = t & 31, ro = t >> 5;                 // ro 0..15
    float4 xv[2];
    #pragma unroll
    for (int k = 0; k < 2; ++k) {
        int node = g * 32 + ro + k * 16;
        xv[k] = (node < n) ? x4[(size_t)node * (F_IN / 4) + c4]
                           : make_float4(0.f, 0.f, 0.f, 0.f);
    }

    uint4* bm4 = (uint4*)u.bm;
    for (int i = t; i < (32 * WPR) / 4; i += 512)
        bm4[i] = make_uint4(0u, 0u, 0u, 0u);
    if (t < 32) dcnt[t] = 0;
    __syncthreads();

    {
        int b = t >> 2, q = t & 3;                // 4 threads per run
        int lo = lofs_t[(size_t)g       * SBLK + b];
        int hi = lofs_t[(size_t)(g + 1) * SBLK + b];
        const unsigned* mo = blockout + (size_t)b * rcap;
        for (int i = lo + q; i < hi; i += 4) {
            unsigned w = mo[i];
            unsigned lrow = (w >> 16) & 31u, col = w & 0xFFFFu;
            unsigned bit = 1u << (col & 31);
            unsigned old = atomicOr(&u.bm[lrow * WPR + (col >> 5)], bit);
            if (!(old & bit)) atomicAdd(&dcnt[lrow], 1);
        }
    }
    __syncthreads();

    if (t < 32) {
        float dv = 1.0f / sqrtf((float)dcnt[t]);   // deg==0 -> inf, matches ref
        dloc[t] = dv;
        int node = g * 32 + t;
        if (node < n) dinv[node] = dv;
    }
    __syncthreads();

    float4 acc = make_float4(0.f, 0.f, 0.f, 0.f);
    #pragma unroll
    for (int k = 0; k < 2; ++k) {
        int node = g * 32 + ro + k * 16;
        if (node < n) {
            float dv = dloc[ro + k * 16];
            acc.x += dv * xv[k].x; acc.y += dv * xv[k].y;
            acc.z += dv * xv[k].z; acc.w += dv * xv[k].w;
        }
    }
    __syncthreads();                      // bm reads done; reuse LDS as scratch
    u.red[ro][c4] = acc;
    __syncthreads();
    if (ro == 0) {
        float4 s = u.red[0][c4];
        #pragma unroll
        for (int k = 1; k < 16; ++k) {
            float4 vv = u.red[k][c4];
            s.x += vv.x; s.y += vv.y; s.z += vv.z; s.w += vv.w;
        }
        int slot = g & (NSLOT - 1);
        atomicAdd(&sacc[((size_t)((c4 * 4 + 0) * NSLOT + slot)) * LINE8],
                  (unsigned long long)(long long)llrint((double)s.x * SCALE));
        atomicAdd(&sacc[((size_t)((c4 * 4 + 1) * NSLOT + slot)) * LINE8],
                  (unsigned long long)(long long)llrint((double)s.y * SCALE));
        atomicAdd(&sacc[((size_t)((c4 * 4 + 2) * NSLOT + slot)) * LINE8],
                  (unsigned long long)(long long)llrint((double)s.z * SCALE));
        atomicAdd(&sacc[((size_t)((c4 * 4 + 3) * NSLOT + slot)) * LINE8],
                  (unsigned long long)(long long)llrint((double)s.w * SCALE));
    }
}

// ---------------------------------------------------------------------------
// O (fused): decode s (exact int64 sum of 8 slots), GEMV agg = s·W,
// grid-stride output. 608 blocks (write-phase parallelism doubled vs R22;
// redundant per-block GEMV is trivial).
// ---------------------------------------------------------------------------
__global__ __launch_bounds__(256)
void k_gemv_outer(const unsigned long long* __restrict__ sacc,
                  const float* __restrict__ W, const float* __restrict__ bias,
                  const float* __restrict__ dinv,
                  float4* __restrict__ out4, int n) {
    __shared__ float s[F_IN];
    __shared__ __align__(16) float aggL[F_OUT];
    int t = threadIdx.x;
    if (t < F_IN) {
        long long v = 0;
        #pragma unroll
        for (int j = 0; j < NSLOT; ++j)
            v += (long long)sacc[((size_t)(t * NSLOT + j)) * LINE8];
        s[t] = (float)((double)v * (1.0 / SCALE));
    }
    __syncthreads();

    {
        float a = 0.f;
        #pragma unroll 8
        for (int k = 0; k < F_IN; ++k)
            a = fmaf(s[k], W[(size_t)k * F_OUT + t], a);
        aggL[t] = a;
    }
    __syncthreads();

    int f4 = t & 63;                      // invariant: grid stride % 64 == 0
    float4 ag = ((const float4*)aggL)[f4];
    float4 b4 = ((const float4*)bias)[f4];
    int total4 = n * (F_OUT / 4);
    int gs = (int)gridDim.x * 256;
    for (int i = (int)blockIdx.x * 256 + t; i < total4; i += gs) {
        float d = dinv[i >> 6];           // 64 consecutive lanes share node
        float4 o;
        o.x = fmaf(d, ag.x, b4.x);
        o.y = fmaf(d, ag.y, b4.y);
        o.z = fmaf(d, ag.z, b4.z);
        o.w = fmaf(d, ag.w, b4.w);
        out4[i] = o;
    }
}

// ===========================================================================
// Fallback (odd sizes / tiny workspace): round-4 global-bitmap path.
// ===========================================================================
__global__ __launch_bounds__(256)
void k_zero_simple(float4* __restrict__ p, size_t n4) {
    size_t i = (size_t)blockIdx.x * blockDim.x + threadIdx.x;
    size_t stride = (size_t)gridDim.x * blockDim.x;
    float4 z = make_float4(0.f, 0.f, 0.f, 0.f);
    for (; i < n4; i += stride) p[i] = z;
}
__global__ void k_set_bits_simple(const int* __restrict__ ei, int E,
                                  unsigned* __restrict__ bm, int r0, int r1,
                                  int row_words) {
    int e = blockIdx.x * blockDim.x + threadIdx.x;
    if (e >= E) return;
    int a = ei[e];
    int b = ei[E + e];
    if (a >= r0 && a < r1)
        atomicOr(&bm[(size_t)(a - r0) * row_words + (b >> 5)], 1u << (b & 31));
    if (b >= r0 && b < r1)
        atomicOr(&bm[(size_t)(b - r0) * row_words + (a >> 5)], 1u << (a & 31));
}
__global__ __launch_bounds__(256)
void k_degree_simple(const unsigned* __restrict__ bm, float* __restrict__ dinv,
                     int r0, int rows, int row_words) {
    int wave = threadIdx.x >> 6;
    int lane = threadIdx.x & 63;
    int row  = blockIdx.x * 4 + wave;
    if (row >= rows) return;
    const unsigned* p = bm + (size_t)row * row_words;
    int cnt = 0;
    for (int w = lane; w < row_words; w += 64)
        cnt += __popc(p[w]);
    #pragma unroll
    for (int off = 32; off > 0; off >>= 1)
        cnt += __shfl_down(cnt, off, 64);
    if (lane == 0)
        dinv[r0 + row] = 1.0f / sqrtf((float)cnt);
}
__global__ __launch_bounds__(256)
void k_colsum_simple(const float4* __restrict__ x4, const float* __restrict__ dinv,
                     float4* __restrict__ partial4, int n) {
    __shared__ float4 lds[8][32];
    int t = threadIdx.x;
    int c4 = t & 31;
    int ro = t >> 5;
    int rows_per = (n + (int)gridDim.x - 1) / (int)gridDim.x;
    int rbeg = blockIdx.x * rows_per;
    int rend = rbeg + rows_per; if (rend > n) rend = n;
    float4 acc = make_float4(0.f, 0.f, 0.f, 0.f);
    for (int r = rbeg + ro; r < rend; r += 8) {
        float dv = dinv[r];
        float4 v = x4[(size_t)r * (F_IN / 4) + c4];
        acc.x += dv * v.x; acc.y += dv * v.y;
        acc.z += dv * v.z; acc.w += dv * v.w;
    }
    lds[ro][c4] = acc;
    __syncthreads();
    if (ro == 0) {
        float4 s = lds[0][c4];
        #pragma unroll
        for (int g = 1; g < 8; ++g) {
            float4 v = lds[g][c4];
            s.x += v.x; s.y += v.y; s.z += v.z; s.w += v.w;
        }
        partial4[(size_t)blockIdx.x * (F_IN / 4) + c4] = s;
    }
}
__global__ __launch_bounds__(1024)
void k_reduce_agg(const float4* __restrict__ partial4, int nparts,
                  const float* __restrict__ W, float* __restrict__ agg) {
    __shared__ float4 lds[32][32];
    __shared__ float s[F_IN];
    __shared__ float aggLds[4][F_OUT];
    int t = threadIdx.x;
    int c4 = t & 31;
    int g  = t >> 5;
    {
        float4 acc = make_float4(0.f, 0.f, 0.f, 0.f);
        for (int b = g; b < nparts; b += 32) {
            float4 v = partial4[(size_t)b * (F_IN / 4) + c4];
            acc.x += v.x; acc.y += v.y; acc.z += v.z; acc.w += v.w;
        }
        lds[g][c4] = acc;
    }
    __syncthreads();
    for (int st = 16; st > 0; st >>= 1) {
        if (g < st) {
            float4 o = lds[g + st][c4];
            float4 v = lds[g][c4];
            v.x += o.x; v.y += o.y; v.z += o.z; v.w += o.w;
            lds[g][c4] = v;
        }
        __syncthreads();
    }
    if (g == 0) {
        float4 v = lds[0][c4];
        s[c4 * 4 + 0] = v.x; s[c4 * 4 + 1] = v.y;
        s[c4 * 4 + 2] = v.z; s[c4 * 4 + 3] = v.w;
    }
    __syncthreads();
    {
        int f  = t & 255;
        int kg = t >> 8;
        float acc = 0.f;
        #pragma unroll 8
        for (int k = kg * 32; k < kg * 32 + 32; ++k)
            acc += s[k] * W[(size_t)k * F_OUT + f];
        aggLds[kg][f] = acc;
    }
    __syncthreads();
    if (t < F_OUT)
        agg[t] = aggLds[0][t] + aggLds[1][t] + aggLds[2][t] + aggLds[3][t];
}
__global__ void k_outer(const float* __restrict__ dinv,
                        const float* __restrict__ agg,
                        const float* __restrict__ bias,
                        float4* __restrict__ out4, int n) {
    int i = blockIdx.x * blockDim.x + threadIdx.x;
    const int per_row = F_OUT / 4;
    int total = n * per_row;
    if (i >= total) return;
    int node = i >> 6;
    int f4   = i & 63;
    float d = dinv[node];
    float4 a  = ((const float4*)agg)[f4];
    float4 bb = ((const float4*)bias)[f4];
    float4 o;
    o.x = fmaf(d, a.x, bb.x);
    o.y = fmaf(d, a.y, bb.y);
    o.z = fmaf(d, a.z, bb.z);
    o.w = fmaf(d, a.w, bb.w);
    out4[i] = o;
}

// ---------------------------------------------------------------------------
static inline size_t align_up(size_t v, size_t a) { return (v + a - 1) & ~(a - 1); }

extern "C" void kernel_launch(void* const* d_in, const int* in_sizes, int n_in,
                              void* d_out, int out_size, void* d_ws, size_t ws_size,
                              hipStream_t stream) {
    const float* x    = (const float*)d_in[0];
    const int*   ei   = (const int*)  d_in[1];
    const float* W    = (const float*)d_in[2];
    const float* bias = (const float*)d_in[3];

    const int n = in_sizes[0] / F_IN;     // 12000
    const int E = in_sizes[1] / 2;        // 384000
    const int G = (n + 31) >> GBITS;      // 375
    const int C = (E + SBLK - 1) / SBLK;  // edges per scatter block (3000)
    const int rcap = (int)align_up((size_t)(2 * C), 64);  // region words (exact bound)

    char* ws = (char*)d_ws;
    size_t off_b = 0;
    float* dinv = (float*)(ws + off_b); off_b = align_up(off_b + (size_t)n * 4, 256);
    unsigned long long* sacc = (unsigned long long*)(ws + off_b);
    off_b = align_up(off_b + (size_t)F_IN * NSLOT * LINE8 * 8, 256);   // 64 KB
    int* lofs_t = (int*)(ws + off_b); off_b = align_up(off_b + (size_t)(G + 1) * SBLK * 4, 256);
    unsigned* blockout = (unsigned*)(ws + off_b);
    size_t need = off_b + (size_t)SBLK * rcap * 4;

    bool fast = (G <= G_MAX) && (((n + 31) >> 5) <= WPR) && (n <= 65536) &&
                (2 * C <= STAGE_CAP) && (C <= EPT * STHR) && (need <= ws_size);

    if (fast) {
        k_scatter_blockout<<<SBLK, STHR, 0, stream>>>(ei, E, G, lofs_t,
                                                      blockout, sacc, rcap);
        k_dedup_colsum<<<G, 512, 0, stream>>>(blockout, lofs_t, rcap,
                                              (const float4*)x, dinv, sacc,
                                              n, G);
        k_gemv_outer<<<608, 256, 0, stream>>>(sacc, W, bias, dinv,
                                              (float4*)d_out, n);
        return;
    }

    // ---- fallback: global-bitmap path ----
    const int row_words = (int)align_up((size_t)((n + 31) / 32), 64);
    const int NB = 512;
    size_t off_f = 0;
    float* dinv_f = (float*)(ws + off_f); off_f = align_up(off_f + (size_t)n * 4, 256);
    float* agg_f  = (float*)(ws + off_f); off_f = align_up(off_f + (size_t)F_OUT * 4, 256);
    float4* part_f = (float4*)(ws + off_f); off_f = align_up(off_f + (size_t)NB * F_IN * 4, 256);
    unsigned* bm = (unsigned*)(ws + off_f);
    size_t avail = (ws_size > off_f) ? (ws_size - off_f) : 0;
    long long fit = (long long)(avail / ((size_t)row_words * 4));
    int rows_per_chunk = (fit >= n) ? n : (fit > 0 ? (int)fit : 1);
    for (int r0 = 0; r0 < n; r0 += rows_per_chunk) {
        int rows = n - r0; if (rows > rows_per_chunk) rows = rows_per_chunk;
        size_t n4 = (size_t)rows * row_words / 4;
        int zgrid = (int)((n4 + 255) / 256); if (zgrid > 2048) zgrid = 2048;
        k_zero_simple<<<zgrid, 256, 0, stream>>>((float4*)bm, n4);
        k_set_bits_simple<<<(E + 255) / 256, 256, 0, stream>>>(ei, E, bm, r0, r0 + rows, row_words);
        k_degree_simple<<<(rows + 3) / 4, 256, 0, stream>>>(bm, dinv_f, r0, rows, row_words);
    }
    k_colsum_simple<<<NB, 256, 0, stream>>>((const float4*)x, dinv_f, part_f, n);
    k_reduce_agg<<<1, 1024, 0, stream>>>(part_f, NB, W, agg_f);
    int total4 = n * (F_OUT / 4);
    k_outer<<<(total4 + 255) / 256, 256, 0, stream>>>(dinv_f, agg_f, bias,
                                                      (float4*)d_out, n);
}